// Round 9
// baseline (3842.620 us; speedup 1.0000x reference)
//
#include <hip/hip_runtime.h>
#include <hip/hip_bf16.h>

using bf16 = __hip_bfloat16;
using uint = unsigned int;
typedef __attribute__((ext_vector_type(8))) short short8v;   // 8 x bf16 MFMA operand
typedef __attribute__((ext_vector_type(4))) float float4v;   // MFMA accumulator

__device__ __forceinline__ float b2f(bf16 x){ return __bfloat162float(x); }
__device__ __forceinline__ bf16  f2b(float x){ return __float2bfloat16(x); }
__device__ __forceinline__ uint f2bu(float x){            // bf16 bits, RNE
    uint u = __float_as_uint(x);
    return (u + 0x7fffu + ((u >> 16) & 1u)) >> 16;
}
__device__ __forceinline__ float blo(uint u){ return __uint_as_float(u << 16); }
__device__ __forceinline__ float bhi(uint u){ return __uint_as_float(u & 0xffff0000u); }

// ---------------- problem constants ----------------
constexpr int Mmol = 512, Aat = 64;
constexpr int Nat  = Mmol * Aat;      // 32768
constexpr int NP1  = Nat + 1;
constexpr int Bnd  = Nat * 4;         // 131072
constexpr int BP1  = Bnd + 1;
constexpr int Hd   = 300;
constexpr int AF   = 133, BFd = 147;
constexpr int NB   = 6;
constexpr int GSL  = 38;              // h-elems per GRU slice (8 x 38 = 304 >= 300)

// =====================================================================
// MFMA GEMM: C[n,h] = act( A[n,K] @ Wp[h,Kp]^T (+bias)(+res) )
// R5 form (proven 226us, 56 VGPR): 1-D grid + chunked XCD-bijective
// remap (A-side fetched once per XCD). R6's register pipeline stays
// REVERTED (it spilled: WRITE_SIZE 81->237MB).
// =====================================================================
template<int AM, bool RELU, bool BIAS, bool RES, bool OUTBF16, bool DUAL, int TAILK>
__global__ __launch_bounds__(256) void mgemm(
    const bf16* __restrict__ Abh, const float* __restrict__ MAf, const bf16* __restrict__ MBh,
    const int* __restrict__ g1, const int* __restrict__ g2,
    const bf16* __restrict__ Wp, const float* __restrict__ bias, const bf16* __restrict__ res,
    void* __restrict__ Cp, bf16* __restrict__ Cp2, int n, int K, int Kp, int h)
{
    const int  NX = (h + 63) >> 6;
    const long NY = ((long)n + 127) >> 7;
    const long J  = (long)NX * NY;
    const long job = (long)(blockIdx.x & 7) * (gridDim.x >> 3) + (blockIdx.x >> 3);
    if (job >= J) return;                       // block-uniform, no barriers
    const int  bx = (int)(job % NX);
    const long by = job / NX;
    const long rowBase = by * 128;
    const long colBase = (long)bx * 64;

    const int tid  = threadIdx.x;
    const int lane = tid & 63, w = tid >> 6;
    const int l15  = lane & 15, quad = lane >> 4;

    long arow[2], ga[2], gb[2];
    #pragma unroll
    for (int mt = 0; mt < 2; ++mt) {
        long r = rowBase + w * 32 + mt * 16 + l15;
        if (r >= n) r = n - 1;               // clamped rows: garbage acc, never stored
        arow[mt] = r;
        if constexpr (AM == 3) { ga[mt] = g1[r]; gb[mt] = g2[r]; }
        else { ga[mt] = 0; gb[mt] = 0; }
    }

    const bf16* wp0 = Wp + (colBase + l15) * (long)Kp + quad * 8;

    float4v acc[2][4];
    #pragma unroll
    for (int mt = 0; mt < 2; ++mt)
        #pragma unroll
        for (int nt = 0; nt < 4; ++nt)
            acc[mt][nt] = (float4v){0.f, 0.f, 0.f, 0.f};

    const int ktiles = (K + 31) / 32;
    for (int kt = 0; kt < ktiles; ++kt) {
        const int kb = kt * 32;
        const int koff = kb + quad * 8;
        short8v bfr[4];
        #pragma unroll
        for (int nt = 0; nt < 4; ++nt)
            bfr[nt] = *(const short8v*)(wp0 + (long)nt * 16 * Kp + kb);
        short8v af[2];
        if constexpr (AM == 0) {
            #pragma unroll
            for (int mt = 0; mt < 2; ++mt) {
                const bf16* p = Abh + arow[mt] * (long)K + koff;
                union { uint2 u2[2]; short8v s; } t;
                t.u2[0] = *(const uint2*)p;
                t.u2[1] = *(const uint2*)(p + 4);
                af[mt] = t.s;
            }
        } else {   // AM == 3 fused gather-sub
            #pragma unroll
            for (int mt = 0; mt < 2; ++mt) {
                const float* pa = MAf + ga[mt] * 300 + koff;
                const bf16*  pb = MBh + gb[mt] * 300 + koff;
                const float4 m0 = *(const float4*)pa;
                const float4 m1 = *(const float4*)(pa + 4);
                const uint2  u0 = *(const uint2*)pb;
                const uint2  u1 = *(const uint2*)(pb + 4);
                float v[8];
                v[0] = m0.x - blo(u0.x); v[1] = m0.y - bhi(u0.x);
                v[2] = m0.z - blo(u0.y); v[3] = m0.w - bhi(u0.y);
                v[4] = m1.x - blo(u1.x); v[5] = m1.y - bhi(u1.x);
                v[6] = m1.z - blo(u1.y); v[7] = m1.w - bhi(u1.y);
                short8v s;
                #pragma unroll
                for (int j = 0; j < 8; ++j) s[j] = (short)f2bu(v[j]);
                af[mt] = s;
            }
        }
        if constexpr (TAILK != 0) {
            if (kb + 32 > K) {               // uniform branch, last tile only
                #pragma unroll
                for (int j = 0; j < 8; ++j)
                    if (koff + j >= K) { af[0][j] = 0; af[1][j] = 0; }
            }
        }
        #pragma unroll
        for (int mt = 0; mt < 2; ++mt)
            #pragma unroll
            for (int nt = 0; nt < 4; ++nt)
                acc[mt][nt] = __builtin_amdgcn_mfma_f32_16x16x32_bf16(
                    af[mt], bfr[nt], acc[mt][nt], 0, 0, 0);
    }

    float biasv[4];
    #pragma unroll
    for (int nt = 0; nt < 4; ++nt) {
        const long c = colBase + nt * 16 + l15;
        biasv[nt] = (BIAS && c < h) ? bias[c] : 0.f;
    }
    #pragma unroll
    for (int mt = 0; mt < 2; ++mt) {
        #pragma unroll
        for (int reg = 0; reg < 4; ++reg) {
            const long r = rowBase + w * 32 + mt * 16 + quad * 4 + reg;
            if (r < n) {
                #pragma unroll
                for (int nt = 0; nt < 4; ++nt) {
                    const long c = colBase + nt * 16 + l15;
                    if (c < h) {
                        float v = acc[mt][nt][reg];
                        if constexpr (RES)  v += b2f(res[r * (long)h + c]);
                        if constexpr (BIAS) v += biasv[nt];
                        if constexpr (RELU) v = fmaxf(v, 0.f);
                        if constexpr (DUAL) {
                            ((float*)Cp)[r * (long)h + c] = v;
                            Cp2[r * (long)h + c] = f2b(fmaxf(v, 0.f));
                        } else if constexpr (OUTBF16) {
                            ((bf16*)Cp)[r * (long)h + c] = f2b(v);
                        } else {
                            ((float*)Cp)[r * (long)h + c] = v;
                        }
                    }
                }
            }
        }
    }
}

// =====================================================================
__global__ __launch_bounds__(256) void pack_w(const float* __restrict__ W, bf16* __restrict__ Wp,
                                              int h, int K, long total, int Kp)
{
    const long idx = (long)blockIdx.x * 256 + threadIdx.x;
    if (idx >= total) return;
    const long r = idx / Kp;
    const int kk = (int)(idx - r * Kp);
    Wp[idx] = (r < h && kk < K) ? f2b(W[r * (long)K + kk]) : f2b(0.f);
}

// lr_W [300][900] -> Wp [320][960] bf16, segment-padded (3 x 300->320)
__global__ __launch_bounds__(256) void pack_lrw(const float* __restrict__ W, bf16* __restrict__ Wp)
{
    const int idx = blockIdx.x * 256 + threadIdx.x;
    if (idx >= 320 * 960) return;
    const int r = idx / 960, c = idx - r * 960;
    const int seg = c / 320, kk = c - seg * 320;
    Wp[idx] = (r < 300 && kk < 300) ? f2b(W[r * 900 + seg * 300 + kk]) : f2b(0.f);
}

// pack_gws: gWhh [900][300] f32 -> 8 slice-strips [8][128][320] bf16.
// Strip s row r (r = g*38 + l, g=gate 0..2): W row g*300 + (s*38 + l).
// Rows >=114, j>=300 and k>=300 are zero (K-pad makes h pad cols harmless).
__global__ __launch_bounds__(256) void pack_gws(const float* __restrict__ W, bf16* __restrict__ Wp)
{
    const int idx = blockIdx.x * 256 + threadIdx.x;
    if (idx >= 8 * 128 * 320) return;
    const int k = idx % 320;
    const int r = (idx / 320) & 127;
    const int s = idx / (320 * 128);
    const int g = r / GSL, l = r - g * GSL;
    const int j = s * GSL + l;
    bf16 v = f2b(0.f);
    if (r < 114 && j < 300 && k < 300)
        v = f2b(W[(g * 300 + j) * 300 + k]);
    Wp[idx] = v;
}

// =====================================================================
// f32 VALU GEMM (IA only, k=133; keeps f_atoms at full precision)
// R5: chunked XCD remap (col-tiles of one row-stripe on one XCD).
// =====================================================================
constexpr int BMr = 256, BNc = 64;

__global__ __launch_bounds__(256) void gemm_ia(
    const float* __restrict__ A, const float* __restrict__ W,
    float* __restrict__ Cp, int n, int k, int h)
{
    __shared__ float As[16][BMr];
    __shared__ float Ws[16][BNc];

    const int  NC = (h + BNc - 1) / BNc;
    const long NR = ((long)n + BMr - 1) / BMr;
    const long J  = (long)NC * NR;
    const long job = (long)(blockIdx.x & 7) * (gridDim.x >> 3) + (blockIdx.x >> 3);
    if (job >= J) return;                       // block-uniform, before barriers
    const int  c0 = (int)(job % NC);
    const long rt = job / NC;
    const long rowBase = rt * BMr;
    const long colBase = (long)c0 * BNc;

    const int tid = threadIdx.x;
    const int tx = tid & 7, ty = tid >> 3;

    const long grow = rowBase + tid;
    const bool rv = grow < n;
    const int wcol = tid & 63, kq = tid >> 6;
    const long gcol = colBase + wcol;
    const bool cvv = gcol < h;

    float acc[8][8] = {};

    const int ktiles = (k + 15) / 16;
    for (int kt = 0; kt < ktiles; ++kt) {
        const int kb = kt * 16;
        __syncthreads();
        const float* ap = A + grow * (long)k + kb;
        #pragma unroll
        for (int c = 0; c < 16; ++c)
            As[c][tid] = (rv && kb + c < k) ? ap[c] : 0.f;
        #pragma unroll
        for (int c = 0; c < 4; ++c) {
            const int kk = kb + kq * 4 + c;
            Ws[kq * 4 + c][wcol] = (cvv && kk < k) ? W[gcol * (long)k + kk] : 0.f;
        }
        __syncthreads();
        #pragma unroll
        for (int kk = 0; kk < 16; ++kk) {
            const float4 a0 = *(const float4*)&As[kk][ty * 8];
            const float4 a1 = *(const float4*)&As[kk][ty * 8 + 4];
            const float4 b0 = *(const float4*)&Ws[kk][tx * 8];
            const float4 b1 = *(const float4*)&Ws[kk][tx * 8 + 4];
            const float aa[8] = {a0.x,a0.y,a0.z,a0.w,a1.x,a1.y,a1.z,a1.w};
            const float bb[8] = {b0.x,b0.y,b0.z,b0.w,b1.x,b1.y,b1.z,b1.w};
            #pragma unroll
            for (int i = 0; i < 8; ++i)
                #pragma unroll
                for (int j = 0; j < 8; ++j)
                    acc[i][j] = fmaf(aa[i], bb[j], acc[i][j]);
        }
    }
    #pragma unroll
    for (int i = 0; i < 8; ++i) {
        const long r = rowBase + ty * 8 + i;
        if (r < n) {
            #pragma unroll
            for (int j = 0; j < 8; ++j) {
                const long c = colBase + tx * 8 + j;
                if (c < h) Cp[r * (long)h + c] = fmaxf(acc[i][j], 0.f);
            }
        }
    }
}

// =====================================================================
template<bool ADD>
__global__ __launch_bounds__(320) void agg_kernel(
    const bf16* __restrict__ MB, const int* __restrict__ a2b,
    const float* __restrict__ src, float* __restrict__ out, int rowoff)
{
    const int hh = threadIdx.x;
    if (hh >= Hd) return;
    const long atom = (long)blockIdx.x + rowoff;
    const int* nb = a2b + atom * NB;
    float s = 0.f, mx = -1e30f;
    #pragma unroll
    for (int j = 0; j < NB; ++j) {
        const float v = b2f(MB[(long)nb[j] * Hd + hh]);
        s += v; mx = fmaxf(mx, v);
    }
    const float agg = s * mx;
    const long o = (long)blockIdx.x * Hd + hh;
    if constexpr (ADD) out[o] = src[atom * Hd + hh] + agg;
    else               out[o] = agg;
}

// cc_build: CC[r][0:300)=sum*max(MB1 gather), [320:620)=MA, [640:940)=IA, pads 0
__global__ __launch_bounds__(320) void cc_build(
    const bf16* __restrict__ MB, const int* __restrict__ a2b,
    const float* __restrict__ MA, const float* __restrict__ IA,
    bf16* __restrict__ CC)
{
    const int hh = threadIdx.x;
    const long r = blockIdx.x;          // 0..Nat-1, atom = r+1
    bf16* cr = CC + r * 960;
    if (hh < Hd) {
        const long atom = r + 1;
        const int* nb = a2b + atom * NB;
        float s = 0.f, mx = -1e30f;
        #pragma unroll
        for (int j = 0; j < NB; ++j) {
            const float v = b2f(MB[(long)nb[j] * Hd + hh]);
            s += v; mx = fmaxf(mx, v);
        }
        cr[hh]       = f2b(s * mx);
        cr[320 + hh] = f2b(MA[atom * Hd + hh]);
        cr[640 + hh] = f2b(IA[atom * Hd + hh]);
    } else {
        const int p = hh - Hd;          // 0..19
        cr[300 + p] = f2b(0.f);
        cr[620 + p] = f2b(0.f);
        cr[940 + p] = f2b(0.f);
    }
}

__global__ __launch_bounds__(320) void h0_kernel(const float* __restrict__ node, float* __restrict__ h0)
{
    const int hh = threadIdx.x;
    if (hh >= Hd) return;
    const long m = blockIdx.x;
    float mx = -1e30f;
    for (int a = 0; a < Aat; ++a)
        mx = fmaxf(mx, node[(m * Aat + a) * (long)Hd + hh]);
    h0[m * Hd + hh] = mx;
}

__global__ __launch_bounds__(320) void mean_kernel(const float* __restrict__ AH, float* __restrict__ out)
{
    const int hh = threadIdx.x;
    if (hh >= Hd) return;
    const long m = blockIdx.x;
    float s = 0.f;
    for (int a = 0; a < Aat; ++a)
        s += AH[(m * Aat + a) * (long)Hd + hh];
    out[m * Hd + hh] = s * (1.f / 64.f);
}

// =====================================================================
// hinit: h0 f32 [512][300] -> h_f32 [2dir][512][320] + h_bf16 buf0;
// buf1 zeroed. Pads (j>=300) zero. Also zeroes the GRU barrier counter.
// =====================================================================
__global__ __launch_bounds__(320) void hinit_kernel(const float* __restrict__ h0,
                                                    float* __restrict__ hf, bf16* __restrict__ hb,
                                                    uint* __restrict__ bar)
{
    const int j = threadIdx.x;           // 0..319
    const long m = blockIdx.x;
    const int dir = blockIdx.y;
    if (m == 0 && dir == 0 && j == 0) bar[0] = 0u;
    const float v = (j < 300) ? h0[m * 300 + j] : 0.f;
    hf[((long)dir * 512 + m) * 320 + j] = v;
    hb[((long)dir * 512 + m) * 320 + j] = f2b(v);                    // buf 0
    hb[((long)(2 + dir) * 512 + m) * 320 + j] = f2b(0.f);            // buf 1
}

// =====================================================================
// gru_pers: R8 persistent GRU, PLAIN launch + software global barrier.
// R7's hipLaunchCooperativeKernel killed the container (coop + graph
// capture); replaced with an atomic barrier. Co-residency is structural:
// 256 blocks x 88.6KB LDS -> exactly 1 block/CU on 256 CUs.
// NEW: W-strip register residency. Per thread the 20 MFMA A-fragments
// = 320B = 80 VGPR -> whole 80KB strip lives in the block's registers,
// loaded ONCE for all 64 steps (kills the per-step 82KB L2 W-stream,
// the R1-R3 granule wall). Barrier: arrive = device-scope atomicAdd
// (monotonic counter, zeroed by hinit each replay); tid0 spins on an
// agent-scope atomic load with s_sleep + bounded spin (no-hang);
// release = __threadfence (L2 wb) before arrive, acquire = __threadfence
// (L2 inv) after. Gate math / decomposition identical to the validated
// step kernel.
// =====================================================================
__global__ __launch_bounds__(256) void gru_pers(
    const bf16* __restrict__ gi_f, const bf16* __restrict__ gi_b,
    const bf16* __restrict__ wsf, const bf16* __restrict__ wsb,   // [8][128][320]
    const float* __restrict__ bhh_f, const float* __restrict__ bhh_b,
    float* __restrict__ hf, bf16* __restrict__ hb, bf16* __restrict__ out,
    uint* __restrict__ bar, int force)
{
    const int slice = blockIdx.x & 7;
    const int dir   = (blockIdx.x >> 3) & 1;
    const int m0    = (blockIdx.x >> 4) * 32;

    const bf16*  WS  = (dir ? wsb : wsf) + (long)slice * 128 * 320;
    const bf16*  gi  = dir ? gi_b : gi_f;
    const float* bhh = dir ? bhh_b : bhh_f;
    float* hfd = hf + (long)dir * 512 * 320;

    __shared__ float GHs[128][36];      // gh staging [Wrow][mol], pad 36
    __shared__ uint  Hs[32][164];       // h tile [mol][160 uints], pad 164
    __shared__ float ldspad[12288];     // 48KB pad -> ~88.6KB total -> 1 block/CU

    const int tid  = threadIdx.x;
    const int lane = tid & 63, w = tid >> 6;     // w: 0..3
    const int l15  = lane & 15, quad = lane >> 4;

    if (force) {                        // never taken; keeps ldspad allocated
        ldspad[tid] = (float)tid;
        GHs[0][0] = ldspad[(tid + force) & 4095];
    }

    // ---- W strip -> registers, once (wA: mt=w, wB: mt=w+4) ----
    short8v wA[10], wB[10];
    {
        const bf16* apA = WS + (long)(w * 16 + l15) * 320 + quad * 8;
        const bf16* apB = WS + (long)((w + 4) * 16 + l15) * 320 + quad * 8;
        #pragma unroll
        for (int kf = 0; kf < 10; ++kf) wA[kf] = *(const short8v*)(apA + kf * 32);
        #pragma unroll
        for (int kf = 0; kf < 10; ++kf) wB[kf] = *(const short8v*)(apB + kf * 32);
    }

    // ---- phase-B assignment constants (hoisted; 3 passes x 608 items) ----
    bool ok[3]; int pmol[3], jlA[3], jgA[3];
    float2 brA[3], bzA[3], bnA[3];
    #pragma unroll
    for (int p = 0; p < 3; ++p) {
        const int idx = tid + p * 256;
        bool o = idx < 19 * 32;
        const int mol = o ? idx / 19 : 0;
        const int jp  = o ? idx - mol * 19 : 0;
        const int jl  = jp * 2, jg = slice * GSL + jl;
        if (jg >= 300) o = false;
        ok[p] = o; pmol[p] = mol; jlA[p] = jl; jgA[p] = jg;
        brA[p] = o ? *(const float2*)(bhh + jg)       : make_float2(0.f, 0.f);
        bzA[p] = o ? *(const float2*)(bhh + 300 + jg) : make_float2(0.f, 0.f);
        bnA[p] = o ? *(const float2*)(bhh + 600 + jg) : make_float2(0.f, 0.f);
    }

    for (int t = 0; t < Aat; ++t) {
        const int a = dir ? (Aat - 1 - t) : t;
        const bf16* hbr = hb + ((long)((t & 1) * 2 + dir) * 512) * 320;
        bf16*       hbw = hb + ((long)(((t + 1) & 1) * 2 + dir) * 512) * 320;

        // ---- gi prefetch (overlaps h-stage + MFMA) ----
        uint gr[3], gz[3], gn[3];
        #pragma unroll
        for (int p = 0; p < 3; ++p) {
            gr[p] = gz[p] = gn[p] = 0;
            if (ok[p]) {
                const bf16* girow = gi + ((long)(m0 + pmol[p]) * Aat + a) * 900;
                gr[p] = *(const uint*)(girow + jgA[p]);
                gz[p] = *(const uint*)(girow + 300 + jgA[p]);
                gn[p] = *(const uint*)(girow + 600 + jgA[p]);
            }
        }

        // ---- stage h tile (32 mols x 320 bf16) into LDS, coalesced ----
        #pragma unroll
        for (int q = 0; q < 10; ++q) {
            const int idx = tid + q * 256;            // 0..2559
            const int row = idx / 80, c = idx - row * 80;
            const uint2 v = *(const uint2*)(hbr + (long)(m0 + row) * 320 + c * 4);
            *(uint2*)&Hs[row][c * 2] = v;
        }
        __syncthreads();

        // ---- B fragments (h) from LDS ----
        short8v hbf[2][10];
        #pragma unroll
        for (int ct = 0; ct < 2; ++ct)
            #pragma unroll
            for (int kf = 0; kf < 10; ++kf)
                hbf[ct][kf] = *(const short8v*)&Hs[ct * 16 + l15][kf * 16 + quad * 4];

        // ---- MFMA: gh_strip = W_strip(regs) @ h ----
        {
            float4v acc0 = (float4v){0.f, 0.f, 0.f, 0.f};
            float4v acc1 = (float4v){0.f, 0.f, 0.f, 0.f};
            #pragma unroll
            for (int kf = 0; kf < 10; ++kf) {
                acc0 = __builtin_amdgcn_mfma_f32_16x16x32_bf16(wA[kf], hbf[0][kf], acc0, 0, 0, 0);
                acc1 = __builtin_amdgcn_mfma_f32_16x16x32_bf16(wA[kf], hbf[1][kf], acc1, 0, 0, 0);
            }
            #pragma unroll
            for (int reg = 0; reg < 4; ++reg) {
                GHs[w * 16 + quad * 4 + reg][l15]      = acc0[reg];
                GHs[w * 16 + quad * 4 + reg][16 + l15] = acc1[reg];
            }
        }
        {
            float4v acc0 = (float4v){0.f, 0.f, 0.f, 0.f};
            float4v acc1 = (float4v){0.f, 0.f, 0.f, 0.f};
            #pragma unroll
            for (int kf = 0; kf < 10; ++kf) {
                acc0 = __builtin_amdgcn_mfma_f32_16x16x32_bf16(wB[kf], hbf[0][kf], acc0, 0, 0, 0);
                acc1 = __builtin_amdgcn_mfma_f32_16x16x32_bf16(wB[kf], hbf[1][kf], acc1, 0, 0, 0);
            }
            #pragma unroll
            for (int reg = 0; reg < 4; ++reg) {
                GHs[(w + 4) * 16 + quad * 4 + reg][l15]      = acc0[reg];
                GHs[(w + 4) * 16 + quad * 4 + reg][16 + l15] = acc1[reg];
            }
        }
        __syncthreads();

        // ---- phase B: gates + state update ----
        #pragma unroll
        for (int p = 0; p < 3; ++p) {
            if (ok[p]) {
                const int mol = pmol[p], jl = jlA[p], jg = jgA[p];
                const float hr0 = GHs[jl][mol],           hr1 = GHs[jl + 1][mol];
                const float hz0 = GHs[GSL + jl][mol],     hz1 = GHs[GSL + jl + 1][mol];
                const float hn0 = GHs[2 * GSL + jl][mol], hn1 = GHs[2 * GSL + jl + 1][mol];
                float* hop = hfd + (long)(m0 + mol) * 320 + jg;
                const float2 hold = *(const float2*)hop;
                float hnew[2];
                #pragma unroll
                for (int j = 0; j < 2; ++j) {
                    const float ir  = j ? bhi(gr[p]) : blo(gr[p]);
                    const float iz  = j ? bhi(gz[p]) : blo(gz[p]);
                    const float inn = j ? bhi(gn[p]) : blo(gn[p]);
                    const float ghr = j ? hr1 + brA[p].y : hr0 + brA[p].x;
                    const float ghz = j ? hz1 + bzA[p].y : hz0 + bzA[p].x;
                    const float ghn = j ? hn1 + bnA[p].y : hn0 + bnA[p].x;
                    const float rr = 1.f / (1.f + __expf(-(ir + ghr)));
                    const float zz = 1.f / (1.f + __expf(-(iz + ghz)));
                    float nin = inn + rr * ghn;
                    nin = fminf(fmaxf(nin, -15.f), 15.f);
                    const float e2 = __expf(-2.f * nin);
                    const float nnv = (1.f - e2) / (1.f + e2);
                    hnew[j] = (1.f - zz) * nnv + zz * (j ? hold.y : hold.x);
                }
                const uint pk2 = f2bu(hnew[0]) | (f2bu(hnew[1]) << 16);
                *(float2*)hop = make_float2(hnew[0], hnew[1]);
                *(uint*)(hbw + (long)(m0 + mol) * 320 + jg) = pk2;
                *(uint*)(out + ((long)(m0 + mol) * Aat + a) * 600 + (long)dir * 300 + jg) = pk2;
            }
        }

        // ---- software global barrier (skip after last step) ----
        if (t < Aat - 1) {
            __syncthreads();                      // drains this block's stores
            if (tid == 0) {
                __threadfence();                  // release: L2 writeback
                atomicAdd(bar, 1u);               // device-scope arrive
                const uint target = 256u * (uint)(t + 1);
                int spins = 0;
                while (__hip_atomic_load(bar, __ATOMIC_RELAXED,
                                         __HIP_MEMORY_SCOPE_AGENT) < target
                       && spins < 500000) {
                    ++spins;
                    __builtin_amdgcn_s_sleep(2);
                }
            }
            __syncthreads();
            __threadfence();                      // acquire: L2 invalidate
        }
    }
}

// =====================================================================
extern "C" void kernel_launch(void* const* d_in, const int* in_sizes, int n_in,
                              void* d_out, int out_size, void* d_ws, size_t ws_size,
                              hipStream_t stream)
{
    (void)in_sizes; (void)n_in; (void)out_size; (void)ws_size;

    const float* f_atoms  = (const float*)d_in[0];
    const float* f_bonds  = (const float*)d_in[1];
    const int*   a2b      = (const int*)d_in[2];
    const int*   b2a      = (const int*)d_in[3];
    const int*   b2revb   = (const int*)d_in[4];
    const float* W_i_atom = (const float*)d_in[7];
    const float* W_i_bond = (const float*)d_in[8];
    const float* W_h      = (const float*)d_in[9];
    const float* lr_W     = (const float*)d_in[10];
    const float* W_o_W    = (const float*)d_in[11];
    const float* W_o_b    = (const float*)d_in[12];
    const float* gWih_f   = (const float*)d_in[13];
    const float* gWhh_f   = (const float*)d_in[14];
    const float* gbih_f   = (const float*)d_in[15];
    const float* gbhh_f   = (const float*)d_in[16];
    const float* gWih_b   = (const float*)d_in[17];
    const float* gWhh_b   = (const float*)d_in[18];
    const float* gbih_b   = (const float*)d_in[19];
    const float* gbhh_b   = (const float*)d_in[20];

    // ---- workspace: same 4-region footprint as proven R6-R8 (~235.9 MB) ----
    const size_t F32A_B = (size_t)NP1 * Hd * 4;      // 39.32 MB
    const size_t BND_B  = (size_t)BP1 * Hd * 2;      // 78.64 MB
    const size_t H0_B   = (size_t)Mmol * Hd * 4;     // 614,400 B
    const size_t WPM_B  = (size_t)8 * 128 * 320 * 2; // 655,360 B (strip layout)

    size_t off = 0;
    auto alloc = [&](size_t b) { size_t r = off; off += (b + 255) & ~(size_t)255; return r; };
    const size_t r1_o = alloc(F32A_B);       // IA [1-7] -> {H0,strips,NRb,h,bar} [8-12] -> AH [13-14]
    const size_t r2_o = alloc(F32A_B);       // MA [3-7] -> GRU [12-13]
    const size_t r3_o = alloc(BND_B);        // IB/MB1 [2-7] -> NODE [8-9] -> GIF [10-12]
    const size_t r4_o = alloc(BND_B + 4096); // FB16 [1b-2] -> MB0 [4-6] -> CC [7-8] -> GIB [11-12]

    char* ws = (char*)d_ws;
    float* IA   = (float*)(ws + r1_o);
    float* H0p  = (float*)(ws + r1_o);
    bf16*  WPmf = (bf16*)(ws + r1_o + ((H0_B + 255) & ~(size_t)255));
    bf16*  WPmb = (bf16*)((char*)WPmf + ((WPM_B + 255) & ~(size_t)255));
    bf16*  NRb  = (bf16*)(ws + r1_o + (2u << 20));   // +2MB, 19.66MB used
    float* Hf32 = (float*)(ws + r1_o + (23u << 20)); // 1.31MB  [2dir][512][320] f32
    bf16*  Hb16 = (bf16*)(ws + r1_o + (25u << 20));  // 1.31MB  [2buf][2dir][512][320] bf16
    uint*  BAR  = (uint*)(ws + r1_o + (28u << 20));  // barrier counter (GRU phase only)
    float* AH   = (float*)(ws + r1_o);
    float* MAb  = (float*)(ws + r2_o);
    bf16*  GRU  = (bf16*)(ws + r2_o);
    bf16*  IB   = (bf16*)(ws + r3_o);
    bf16*  MB1  = IB;
    float* NODE = (float*)(ws + r3_o);
    bf16*  GIF  = (bf16*)(ws + r3_o);
    bf16*  FB16 = (bf16*)(ws + r4_o);
    bf16*  MB0  = (bf16*)(ws + r4_o);
    bf16*  CC   = (bf16*)(ws + r4_o);
    bf16*  GIB  = (bf16*)(ws + r4_o);
    float* OUT  = (float*)d_out;
    bf16*  WSC  = (bf16*)d_out;        // 614,400 B time-shared packed-weight scratch

    const dim3 blk(256);
    // R5: 1-D XCD-chunked grids (pad to multiple of 8; kernels decode+guard)
    auto grdM = [](int n, int h) {
        long J = (long)((h + 63) / 64) * ((n + 127) / 128);
        return dim3((unsigned)((J + 7) / 8 * 8));
    };
    auto grdF = [](int n, int h) {
        long J = (long)((h + BNc - 1) / BNc) * ((n + BMr - 1) / BMr);
        return dim3((unsigned)((J + 7) / 8 * 8));
    };
    auto pk = [&](const float* W, bf16* Wp, int h, int K, long hp, int Kp) {
        const long tot = hp * Kp;
        pack_w<<<dim3((tot + 255) / 256), blk, 0, stream>>>(W, Wp, h, K, tot, Kp);
    };

    // 1. IA = relu(f_atoms @ W_i_atom^T) -> f32 (VALU, full precision)
    gemm_ia<<<grdF(NP1, Hd), blk, 0, stream>>>(f_atoms, W_i_atom, IA, NP1, AF, Hd);
    // 1b. pack f_bonds -> bf16 [BP1][160]; W_i_bond -> [320][160] @d_out
    pk(f_bonds, FB16, BP1, BFd, BP1, 160);
    pk(W_i_bond, WSC, Hd, BFd, 320, 160);
    // 2. IB = relu(FB16 @ WIB^T)   [MFMA]
    mgemm<0, true, false, false, true, false, 0><<<grdM(BP1, Hd), blk, 0, stream>>>(
        FB16, nullptr, nullptr, nullptr, nullptr, WSC, nullptr, nullptr,
        IB, nullptr, BP1, 160, 160, Hd);
    // 3. MA = IA + sum*max(IB gathered)
    agg_kernel<true><<<NP1, 320, 0, stream>>>(IB, a2b, IA, MAb, 0);
    pk(W_h, WSC, Hd, Hd, 320, 320);
    // 4. MB0 = relu(IB + (MA[b2a]-IB[b2revb]) @ Wh0^T)   [MFMA fused gather]
    mgemm<3, true, false, true, true, false, 12><<<grdM(BP1, Hd), blk, 0, stream>>>(
        nullptr, MAb, IB, b2a, b2revb, WSC, nullptr, IB,
        MB0, nullptr, BP1, Hd, 320, Hd);
    // 5. MA += sum*max(MB0 gathered)
    agg_kernel<true><<<NP1, 320, 0, stream>>>(MB0, a2b, MAb, MAb, 0);
    pk(W_h + 300 * 300, WSC, Hd, Hd, 320, 320);
    // 6. MB1(=IB) = relu(IB + (MA[b2a]-MB0[b2revb]) @ Wh1^T)
    mgemm<3, true, false, true, true, false, 12><<<grdM(BP1, Hd), blk, 0, stream>>>(
        nullptr, MAb, MB0, b2a, b2revb, WSC, nullptr, IB,
        MB1, nullptr, BP1, Hd, 320, Hd);
    // 7. CC = concat3 bf16 (agg(MB1) | MA | IA), segment-padded to 960
    cc_build<<<Nat, 320, 0, stream>>>(MB1, a2b, MAb, IA, CC);
    pack_lrw<<<(320 * 960 + 255) / 256, blk, 0, stream>>>(lr_W, WSC);
    // 8. node = CC @ lrWp^T -> NODE f32 (pre-relu) + NRb bf16 (relu)  [MFMA]
    mgemm<0, false, false, false, false, true, 0><<<grdM(Nat, Hd), blk, 0, stream>>>(
        CC, nullptr, nullptr, nullptr, nullptr, WSC, nullptr, nullptr,
        NODE, NRb, Nat, 960, 960, Hd);
    // 9. h0 + GRU Whh slice-strips (r1: IA dead)
    h0_kernel<<<Mmol, 320, 0, stream>>>(NODE, H0p);
    {
        const int tot = 8 * 128 * 320;
        pack_gws<<<dim3((tot + 255) / 256), blk, 0, stream>>>(gWhh_f, WPmf);
        pack_gws<<<dim3((tot + 255) / 256), blk, 0, stream>>>(gWhh_b, WPmb);
    }
    // 10. GIF = NRb @ gWih_f^T + gbih_f   [MFMA]
    pk(gWih_f, WSC, 900, Hd, 960, 320);
    mgemm<0, false, true, false, true, false, 12><<<grdM(Nat, 900), blk, 0, stream>>>(
        NRb, nullptr, nullptr, nullptr, nullptr, WSC, gbih_f, nullptr,
        GIF, nullptr, Nat, Hd, 320, 900);
    // 11. GIB likewise
    pk(gWih_b, WSC, 900, Hd, 960, 320);
    mgemm<0, false, true, false, true, false, 12><<<grdM(Nat, 900), blk, 0, stream>>>(
        NRb, nullptr, nullptr, nullptr, nullptr, WSC, gbih_b, nullptr,
        GIB, nullptr, Nat, Hd, 320, 900);
    // 12. GRU: h init (+bar=0) + ONE persistent plain-launch kernel
    hinit_kernel<<<dim3(Mmol, 2), 320, 0, stream>>>(H0p, Hf32, Hb16, BAR);
    gru_pers<<<dim3(256), blk, 0, stream>>>(
        GIF, GIB, WPmf, WPmb, gbhh_f, gbhh_b, Hf32, Hb16, GRU, BAR, 0);
    // 13. AH = relu(GRU @ W_o_W^T + W_o_b)   [MFMA]
    pk(W_o_W, WSC, Hd, 600, 320, 608);
    mgemm<0, true, true, false, false, false, 24><<<grdM(Nat, Hd), blk, 0, stream>>>(
        GRU, nullptr, nullptr, nullptr, nullptr, WSC, W_o_b, nullptr,
        AH, nullptr, Nat, 600, 608, Hd);
    // 14. mol_vecs = mean -> d_out
    mean_kernel<<<Mmol, 320, 0, stream>>>(AH, OUT);
}

// Round 10
// 1937.896 us; speedup vs baseline: 1.9829x; 1.9829x over previous
//
#include <hip/hip_runtime.h>
#include <hip/hip_bf16.h>

using bf16 = __hip_bfloat16;
using uint = unsigned int;
typedef __attribute__((ext_vector_type(8))) short short8v;   // 8 x bf16 MFMA operand
typedef __attribute__((ext_vector_type(4))) float float4v;   // MFMA accumulator

__device__ __forceinline__ float b2f(bf16 x){ return __bfloat162float(x); }
__device__ __forceinline__ bf16  f2b(float x){ return __float2bfloat16(x); }
__device__ __forceinline__ uint f2bu(float x){            // bf16 bits, RNE
    uint u = __float_as_uint(x);
    return (u + 0x7fffu + ((u >> 16) & 1u)) >> 16;
}
__device__ __forceinline__ float blo(uint u){ return __uint_as_float(u << 16); }
__device__ __forceinline__ float bhi(uint u){ return __uint_as_float(u & 0xffff0000u); }

// ---------------- problem constants ----------------
constexpr int Mmol = 512, Aat = 64;
constexpr int Nat  = Mmol * Aat;      // 32768
constexpr int NP1  = Nat + 1;
constexpr int Bnd  = Nat * 4;         // 131072
constexpr int BP1  = Bnd + 1;
constexpr int Hd   = 300;
constexpr int AF   = 133, BFd = 147;
constexpr int NB   = 6;
constexpr int GSL  = 38;              // h-elems per GRU slice (8 x 38 = 304 >= 300)

// =====================================================================
// MFMA GEMM: C[n,h] = act( A[n,K] @ Wp[h,Kp]^T (+bias)(+res) )
// R5: 1-D grid + chunked XCD-bijective remap (A-side fetched once/XCD).
// R9: AM=3 k-loop gets a 2-deep gather prefetch, R3-style (flat named
// arrays, unroll-by-2, fully static indexing). R6's struct-by-ref
// version spilled (WRITE 81->237MB); flat arrays did NOT spill in R3's
// gru (120 VGPR clean). Load order per tile: W frags FIRST, then next
// tile's gathers -> the MFMA waitcnt (on W, older) leaves the gather
// prefetch in flight across the compute phase (vmcnt counts in order).
// AM=0 path unchanged. R8's persistent-GRU is reverted: software
// barrier + per-step device fences cost 39us/step (L2 wb+inv each
// step; WRITE 201MB) vs 8.9us/step for kernel-boundary sync.
// =====================================================================
template<int AM, bool RELU, bool BIAS, bool RES, bool OUTBF16, bool DUAL, int TAILK>
__global__ __launch_bounds__(256) void mgemm(
    const bf16* __restrict__ Abh, const float* __restrict__ MAf, const bf16* __restrict__ MBh,
    const int* __restrict__ g1, const int* __restrict__ g2,
    const bf16* __restrict__ Wp, const float* __restrict__ bias, const bf16* __restrict__ res,
    void* __restrict__ Cp, bf16* __restrict__ Cp2, int n, int K, int Kp, int h)
{
    const int  NX = (h + 63) >> 6;
    const long NY = ((long)n + 127) >> 7;
    const long J  = (long)NX * NY;
    const long job = (long)(blockIdx.x & 7) * (gridDim.x >> 3) + (blockIdx.x >> 3);
    if (job >= J) return;                       // block-uniform, no barriers
    const int  bx = (int)(job % NX);
    const long by = job / NX;
    const long rowBase = by * 128;
    const long colBase = (long)bx * 64;

    const int tid  = threadIdx.x;
    const int lane = tid & 63, w = tid >> 6;
    const int l15  = lane & 15, quad = lane >> 4;

    long arow[2], ga[2], gb[2];
    #pragma unroll
    for (int mt = 0; mt < 2; ++mt) {
        long r = rowBase + w * 32 + mt * 16 + l15;
        if (r >= n) r = n - 1;               // clamped rows: garbage acc, never stored
        arow[mt] = r;
        if constexpr (AM == 3) { ga[mt] = g1[r]; gb[mt] = g2[r]; }
        else { ga[mt] = 0; gb[mt] = 0; }
    }

    const bf16* wp0 = Wp + (colBase + l15) * (long)Kp + quad * 8;

    float4v acc[2][4];
    #pragma unroll
    for (int mt = 0; mt < 2; ++mt)
        #pragma unroll
        for (int nt = 0; nt < 4; ++nt)
            acc[mt][nt] = (float4v){0.f, 0.f, 0.f, 0.f};

    const int ktiles = (K + 31) / 32;

    if constexpr (AM == 3) {
        // ---- 2-deep gather-prefetch pipeline (flat arrays, static idx) ----
        float4 m0A[2], m1A[2], m0B[2], m1B[2];
        uint2  u0A[2], u1A[2], u0B[2], u1B[2];
        #pragma unroll
        for (int mt = 0; mt < 2; ++mt) {         // preload tile 0 -> A
            const float* pa = MAf + ga[mt] * 300 + quad * 8;
            const bf16*  pb = MBh + gb[mt] * 300 + quad * 8;
            m0A[mt] = *(const float4*)pa; m1A[mt] = *(const float4*)(pa + 4);
            u0A[mt] = *(const uint2*)pb;  u1A[mt] = *(const uint2*)(pb + 4);
        }
        for (int kt = 0; kt < ktiles; kt += 2) {
            {   // ---- even tile: compute from A, prefetch kt+1 -> B ----
                const int kb = kt * 32, koff = kb + quad * 8;
                short8v bfr[4];
                #pragma unroll
                for (int nt = 0; nt < 4; ++nt)   // W first (older in vmcnt order)
                    bfr[nt] = *(const short8v*)(wp0 + (long)nt * 16 * Kp + kb);
                if (kt + 1 < ktiles) {
                    const int ko2 = koff + 32;
                    #pragma unroll
                    for (int mt = 0; mt < 2; ++mt) {
                        const float* pa = MAf + ga[mt] * 300 + ko2;
                        const bf16*  pb = MBh + gb[mt] * 300 + ko2;
                        m0B[mt] = *(const float4*)pa; m1B[mt] = *(const float4*)(pa + 4);
                        u0B[mt] = *(const uint2*)pb;  u1B[mt] = *(const uint2*)(pb + 4);
                    }
                }
                short8v af[2];
                #pragma unroll
                for (int mt = 0; mt < 2; ++mt) {
                    float v[8];
                    v[0] = m0A[mt].x - blo(u0A[mt].x); v[1] = m0A[mt].y - bhi(u0A[mt].x);
                    v[2] = m0A[mt].z - blo(u0A[mt].y); v[3] = m0A[mt].w - bhi(u0A[mt].y);
                    v[4] = m1A[mt].x - blo(u1A[mt].x); v[5] = m1A[mt].y - bhi(u1A[mt].x);
                    v[6] = m1A[mt].z - blo(u1A[mt].y); v[7] = m1A[mt].w - bhi(u1A[mt].y);
                    short8v s;
                    #pragma unroll
                    for (int j = 0; j < 8; ++j) s[j] = (short)f2bu(v[j]);
                    af[mt] = s;
                }
                if constexpr (TAILK != 0) {
                    if (kb + 32 > K) {
                        #pragma unroll
                        for (int j = 0; j < 8; ++j)
                            if (koff + j >= K) { af[0][j] = 0; af[1][j] = 0; }
                    }
                }
                #pragma unroll
                for (int mt = 0; mt < 2; ++mt)
                    #pragma unroll
                    for (int nt = 0; nt < 4; ++nt)
                        acc[mt][nt] = __builtin_amdgcn_mfma_f32_16x16x32_bf16(
                            af[mt], bfr[nt], acc[mt][nt], 0, 0, 0);
            }
            if (kt + 1 < ktiles) {   // ---- odd tile: compute from B, prefetch kt+2 -> A ----
                const int kb = (kt + 1) * 32, koff = kb + quad * 8;
                short8v bfr[4];
                #pragma unroll
                for (int nt = 0; nt < 4; ++nt)
                    bfr[nt] = *(const short8v*)(wp0 + (long)nt * 16 * Kp + kb);
                if (kt + 2 < ktiles) {
                    const int ko2 = koff + 32;
                    #pragma unroll
                    for (int mt = 0; mt < 2; ++mt) {
                        const float* pa = MAf + ga[mt] * 300 + ko2;
                        const bf16*  pb = MBh + gb[mt] * 300 + ko2;
                        m0A[mt] = *(const float4*)pa; m1A[mt] = *(const float4*)(pa + 4);
                        u0A[mt] = *(const uint2*)pb;  u1A[mt] = *(const uint2*)(pb + 4);
                    }
                }
                short8v af[2];
                #pragma unroll
                for (int mt = 0; mt < 2; ++mt) {
                    float v[8];
                    v[0] = m0B[mt].x - blo(u0B[mt].x); v[1] = m0B[mt].y - bhi(u0B[mt].x);
                    v[2] = m0B[mt].z - blo(u0B[mt].y); v[3] = m0B[mt].w - bhi(u0B[mt].y);
                    v[4] = m1B[mt].x - blo(u1B[mt].x); v[5] = m1B[mt].y - bhi(u1B[mt].x);
                    v[6] = m1B[mt].z - blo(u1B[mt].y); v[7] = m1B[mt].w - bhi(u1B[mt].y);
                    short8v s;
                    #pragma unroll
                    for (int j = 0; j < 8; ++j) s[j] = (short)f2bu(v[j]);
                    af[mt] = s;
                }
                if constexpr (TAILK != 0) {
                    if (kb + 32 > K) {
                        #pragma unroll
                        for (int j = 0; j < 8; ++j)
                            if (koff + j >= K) { af[0][j] = 0; af[1][j] = 0; }
                    }
                }
                #pragma unroll
                for (int mt = 0; mt < 2; ++mt)
                    #pragma unroll
                    for (int nt = 0; nt < 4; ++nt)
                        acc[mt][nt] = __builtin_amdgcn_mfma_f32_16x16x32_bf16(
                            af[mt], bfr[nt], acc[mt][nt], 0, 0, 0);
            }
        }
    } else {
        // ---- AM==0: original serial k-loop (streaming, cache-friendly) ----
        for (int kt = 0; kt < ktiles; ++kt) {
            const int kb = kt * 32;
            const int koff = kb + quad * 8;
            short8v bfr[4];
            #pragma unroll
            for (int nt = 0; nt < 4; ++nt)
                bfr[nt] = *(const short8v*)(wp0 + (long)nt * 16 * Kp + kb);
            short8v af[2];
            #pragma unroll
            for (int mt = 0; mt < 2; ++mt) {
                const bf16* p = Abh + arow[mt] * (long)K + koff;
                union { uint2 u2[2]; short8v s; } t;
                t.u2[0] = *(const uint2*)p;
                t.u2[1] = *(const uint2*)(p + 4);
                af[mt] = t.s;
            }
            if constexpr (TAILK != 0) {
                if (kb + 32 > K) {               // uniform branch, last tile only
                    #pragma unroll
                    for (int j = 0; j < 8; ++j)
                        if (koff + j >= K) { af[0][j] = 0; af[1][j] = 0; }
                }
            }
            #pragma unroll
            for (int mt = 0; mt < 2; ++mt)
                #pragma unroll
                for (int nt = 0; nt < 4; ++nt)
                    acc[mt][nt] = __builtin_amdgcn_mfma_f32_16x16x32_bf16(
                        af[mt], bfr[nt], acc[mt][nt], 0, 0, 0);
        }
    }

    float biasv[4];
    #pragma unroll
    for (int nt = 0; nt < 4; ++nt) {
        const long c = colBase + nt * 16 + l15;
        biasv[nt] = (BIAS && c < h) ? bias[c] : 0.f;
    }
    #pragma unroll
    for (int mt = 0; mt < 2; ++mt) {
        #pragma unroll
        for (int reg = 0; reg < 4; ++reg) {
            const long r = rowBase + w * 32 + mt * 16 + quad * 4 + reg;
            if (r < n) {
                #pragma unroll
                for (int nt = 0; nt < 4; ++nt) {
                    const long c = colBase + nt * 16 + l15;
                    if (c < h) {
                        float v = acc[mt][nt][reg];
                        if constexpr (RES)  v += b2f(res[r * (long)h + c]);
                        if constexpr (BIAS) v += biasv[nt];
                        if constexpr (RELU) v = fmaxf(v, 0.f);
                        if constexpr (DUAL) {
                            ((float*)Cp)[r * (long)h + c] = v;
                            Cp2[r * (long)h + c] = f2b(fmaxf(v, 0.f));
                        } else if constexpr (OUTBF16) {
                            ((bf16*)Cp)[r * (long)h + c] = f2b(v);
                        } else {
                            ((float*)Cp)[r * (long)h + c] = v;
                        }
                    }
                }
            }
        }
    }
}

// =====================================================================
__global__ __launch_bounds__(256) void pack_w(const float* __restrict__ W, bf16* __restrict__ Wp,
                                              int h, int K, long total, int Kp)
{
    const long idx = (long)blockIdx.x * 256 + threadIdx.x;
    if (idx >= total) return;
    const long r = idx / Kp;
    const int kk = (int)(idx - r * Kp);
    Wp[idx] = (r < h && kk < K) ? f2b(W[r * (long)K + kk]) : f2b(0.f);
}

// lr_W [300][900] -> Wp [320][960] bf16, segment-padded (3 x 300->320)
__global__ __launch_bounds__(256) void pack_lrw(const float* __restrict__ W, bf16* __restrict__ Wp)
{
    const int idx = blockIdx.x * 256 + threadIdx.x;
    if (idx >= 320 * 960) return;
    const int r = idx / 960, c = idx - r * 960;
    const int seg = c / 320, kk = c - seg * 320;
    Wp[idx] = (r < 300 && kk < 300) ? f2b(W[r * 900 + seg * 300 + kk]) : f2b(0.f);
}

// pack_gws: gWhh [900][300] f32 -> 8 slice-strips [8][128][320] bf16.
// Strip s row r (r = g*38 + l, g=gate 0..2): W row g*300 + (s*38 + l).
// Rows >=114, j>=300 and k>=300 are zero (K-pad makes h pad cols harmless).
__global__ __launch_bounds__(256) void pack_gws(const float* __restrict__ W, bf16* __restrict__ Wp)
{
    const int idx = blockIdx.x * 256 + threadIdx.x;
    if (idx >= 8 * 128 * 320) return;
    const int k = idx % 320;
    const int r = (idx / 320) & 127;
    const int s = idx / (320 * 128);
    const int g = r / GSL, l = r - g * GSL;
    const int j = s * GSL + l;
    bf16 v = f2b(0.f);
    if (r < 114 && j < 300 && k < 300)
        v = f2b(W[(g * 300 + j) * 300 + k]);
    Wp[idx] = v;
}

// =====================================================================
// f32 VALU GEMM (IA only, k=133; keeps f_atoms at full precision)
// R5: chunked XCD remap (col-tiles of one row-stripe on one XCD).
// =====================================================================
constexpr int BMr = 256, BNc = 64;

__global__ __launch_bounds__(256) void gemm_ia(
    const float* __restrict__ A, const float* __restrict__ W,
    float* __restrict__ Cp, int n, int k, int h)
{
    __shared__ float As[16][BMr];
    __shared__ float Ws[16][BNc];

    const int  NC = (h + BNc - 1) / BNc;
    const long NR = ((long)n + BMr - 1) / BMr;
    const long J  = (long)NC * NR;
    const long job = (long)(blockIdx.x & 7) * (gridDim.x >> 3) + (blockIdx.x >> 3);
    if (job >= J) return;                       // block-uniform, before barriers
    const int  c0 = (int)(job % NC);
    const long rt = job / NC;
    const long rowBase = rt * BMr;
    const long colBase = (long)c0 * BNc;

    const int tid = threadIdx.x;
    const int tx = tid & 7, ty = tid >> 3;

    const long grow = rowBase + tid;
    const bool rv = grow < n;
    const int wcol = tid & 63, kq = tid >> 6;
    const long gcol = colBase + wcol;
    const bool cvv = gcol < h;

    float acc[8][8] = {};

    const int ktiles = (k + 15) / 16;
    for (int kt = 0; kt < ktiles; ++kt) {
        const int kb = kt * 16;
        __syncthreads();
        const float* ap = A + grow * (long)k + kb;
        #pragma unroll
        for (int c = 0; c < 16; ++c)
            As[c][tid] = (rv && kb + c < k) ? ap[c] : 0.f;
        #pragma unroll
        for (int c = 0; c < 4; ++c) {
            const int kk = kb + kq * 4 + c;
            Ws[kq * 4 + c][wcol] = (cvv && kk < k) ? W[gcol * (long)k + kk] : 0.f;
        }
        __syncthreads();
        #pragma unroll
        for (int kk = 0; kk < 16; ++kk) {
            const float4 a0 = *(const float4*)&As[kk][ty * 8];
            const float4 a1 = *(const float4*)&As[kk][ty * 8 + 4];
            const float4 b0 = *(const float4*)&Ws[kk][tx * 8];
            const float4 b1 = *(const float4*)&Ws[kk][tx * 8 + 4];
            const float aa[8] = {a0.x,a0.y,a0.z,a0.w,a1.x,a1.y,a1.z,a1.w};
            const float bb[8] = {b0.x,b0.y,b0.z,b0.w,b1.x,b1.y,b1.z,b1.w};
            #pragma unroll
            for (int i = 0; i < 8; ++i)
                #pragma unroll
                for (int j = 0; j < 8; ++j)
                    acc[i][j] = fmaf(aa[i], bb[j], acc[i][j]);
        }
    }
    #pragma unroll
    for (int i = 0; i < 8; ++i) {
        const long r = rowBase + ty * 8 + i;
        if (r < n) {
            #pragma unroll
            for (int j = 0; j < 8; ++j) {
                const long c = colBase + tx * 8 + j;
                if (c < h) Cp[r * (long)h + c] = fmaxf(acc[i][j], 0.f);
            }
        }
    }
}

// =====================================================================
template<bool ADD>
__global__ __launch_bounds__(320) void agg_kernel(
    const bf16* __restrict__ MB, const int* __restrict__ a2b,
    const float* __restrict__ src, float* __restrict__ out, int rowoff)
{
    const int hh = threadIdx.x;
    if (hh >= Hd) return;
    const long atom = (long)blockIdx.x + rowoff;
    const int* nb = a2b + atom * NB;
    float s = 0.f, mx = -1e30f;
    #pragma unroll
    for (int j = 0; j < NB; ++j) {
        const float v = b2f(MB[(long)nb[j] * Hd + hh]);
        s += v; mx = fmaxf(mx, v);
    }
    const float agg = s * mx;
    const long o = (long)blockIdx.x * Hd + hh;
    if constexpr (ADD) out[o] = src[atom * Hd + hh] + agg;
    else               out[o] = agg;
}

// cc_build: CC[r][0:300)=sum*max(MB1 gather), [320:620)=MA, [640:940)=IA, pads 0
__global__ __launch_bounds__(320) void cc_build(
    const bf16* __restrict__ MB, const int* __restrict__ a2b,
    const float* __restrict__ MA, const float* __restrict__ IA,
    bf16* __restrict__ CC)
{
    const int hh = threadIdx.x;
    const long r = blockIdx.x;          // 0..Nat-1, atom = r+1
    bf16* cr = CC + r * 960;
    if (hh < Hd) {
        const long atom = r + 1;
        const int* nb = a2b + atom * NB;
        float s = 0.f, mx = -1e30f;
        #pragma unroll
        for (int j = 0; j < NB; ++j) {
            const float v = b2f(MB[(long)nb[j] * Hd + hh]);
            s += v; mx = fmaxf(mx, v);
        }
        cr[hh]       = f2b(s * mx);
        cr[320 + hh] = f2b(MA[atom * Hd + hh]);
        cr[640 + hh] = f2b(IA[atom * Hd + hh]);
    } else {
        const int p = hh - Hd;          // 0..19
        cr[300 + p] = f2b(0.f);
        cr[620 + p] = f2b(0.f);
        cr[940 + p] = f2b(0.f);
    }
}

__global__ __launch_bounds__(320) void h0_kernel(const float* __restrict__ node, float* __restrict__ h0)
{
    const int hh = threadIdx.x;
    if (hh >= Hd) return;
    const long m = blockIdx.x;
    float mx = -1e30f;
    for (int a = 0; a < Aat; ++a)
        mx = fmaxf(mx, node[(m * Aat + a) * (long)Hd + hh]);
    h0[m * Hd + hh] = mx;
}

__global__ __launch_bounds__(320) void mean_kernel(const float* __restrict__ AH, float* __restrict__ out)
{
    const int hh = threadIdx.x;
    if (hh >= Hd) return;
    const long m = blockIdx.x;
    float s = 0.f;
    for (int a = 0; a < Aat; ++a)
        s += AH[(m * Aat + a) * (long)Hd + hh];
    out[m * Hd + hh] = s * (1.f / 64.f);
}

// =====================================================================
// hinit: h0 f32 [512][300] -> h_f32 [2dir][512][320] + h_bf16 buf0;
// buf1 zeroed. Pads (j>=300) zero.
// =====================================================================
__global__ __launch_bounds__(320) void hinit_kernel(const float* __restrict__ h0,
                                                    float* __restrict__ hf, bf16* __restrict__ hb)
{
    const int j = threadIdx.x;           // 0..319
    const long m = blockIdx.x;
    const int dir = blockIdx.y;
    const float v = (j < 300) ? h0[m * 300 + j] : 0.f;
    hf[((long)dir * 512 + m) * 320 + j] = v;
    hb[((long)dir * 512 + m) * 320 + j] = f2b(v);                    // buf 0
    hb[((long)(2 + dir) * 512 + m) * 320 + j] = f2b(0.f);            // buf 1
}

// =====================================================================
// gru_step: one GRU timestep for ALL mols/dirs (R4/R5 proven, 8.9us/step
// incl. launch). R7 coop-launch and R8 software-barrier persistent
// variants both refuted (container kill / 39us-per-step fence cost);
// kernel-boundary sync is the measured optimum for this decomposition.
// Slice layout pins each (slice,dir) W-strip to one XCD (slice =
// blockIdx&7 = XCD lane): 164KB hot set per XCD, fully L2-resident.
// =====================================================================
__global__ __launch_bounds__(256) void gru_step(
    const bf16* __restrict__ gi_f, const bf16* __restrict__ gi_b,
    const bf16* __restrict__ wsf, const bf16* __restrict__ wsb,   // [8][128][320]
    const float* __restrict__ bhh_f, const float* __restrict__ bhh_b,
    float* __restrict__ hf, bf16* __restrict__ hb, bf16* __restrict__ out,
    int t, int force)
{
    const int slice = blockIdx.x & 7;
    const int dir   = (blockIdx.x >> 3) & 1;
    const int m0    = (blockIdx.x >> 4) * 32;
    const int a     = dir ? (Aat - 1 - t) : t;

    const bf16*  WS  = (dir ? wsb : wsf) + (long)slice * 128 * 320;
    const bf16*  gi  = dir ? gi_b : gi_f;
    const float* bhh = dir ? bhh_b : bhh_f;
    float* hfd = hf + (long)dir * 512 * 320;
    const int par = t & 1;
    const bf16* hbr = hb + ((long)(par * 2 + dir) * 512) * 320;
    bf16*       hbw = hb + ((long)(((t + 1) & 1) * 2 + dir) * 512) * 320;

    __shared__ float GHs[128][36];      // gh staging [Wrow][mol], pad 36
    __shared__ uint  Hs[32][164];       // h tile [mol][160 uints], pad 164
    __shared__ float ldspad[12288];     // 48KB pad -> ~88KB total -> 1 block/CU

    const int tid  = threadIdx.x;
    const int lane = tid & 63, w = tid >> 6;     // w: 0..3
    const int l15  = lane & 15, quad = lane >> 4;

    if (force) {                        // never taken; keeps ldspad allocated
        ldspad[tid] = (float)tid;
        GHs[0][0] = ldspad[(tid + force) & 4095];
    }

    // ---- stage h tile (32 mols x 320 elems bf16) into LDS, coalesced ----
    #pragma unroll
    for (int q = 0; q < 10; ++q) {
        const int idx = tid + q * 256;            // 0..2559
        const int row = idx / 80, c = idx - row * 80;
        const uint2 v = *(const uint2*)(hbr + (long)(m0 + row) * 320 + c * 4);
        *(uint2*)&Hs[row][c * 2] = v;
    }
    __syncthreads();

    // ---- B fragments (h) from LDS ----
    short8v hbf[2][10];
    #pragma unroll
    for (int ct = 0; ct < 2; ++ct)
        #pragma unroll
        for (int kf = 0; kf < 10; ++kf)
            hbf[ct][kf] = *(const short8v*)&Hs[ct * 16 + l15][kf * 16 + quad * 4];

    // ---- MFMA: gh_strip = W_strip @ h  (2 M-tiles/wave x 2 col-tiles) ----
    #pragma unroll
    for (int mti = 0; mti < 2; ++mti) {
        const int mt = w + mti * 4;
        const bf16* ap = WS + (long)(mt * 16 + l15) * 320 + quad * 8;
        short8v af[10];
        #pragma unroll
        for (int kf = 0; kf < 10; ++kf)
            af[kf] = *(const short8v*)(ap + kf * 32);
        float4v acc0 = (float4v){0.f, 0.f, 0.f, 0.f};
        float4v acc1 = (float4v){0.f, 0.f, 0.f, 0.f};
        #pragma unroll
        for (int kf = 0; kf < 10; ++kf) {
            acc0 = __builtin_amdgcn_mfma_f32_16x16x32_bf16(af[kf], hbf[0][kf], acc0, 0, 0, 0);
            acc1 = __builtin_amdgcn_mfma_f32_16x16x32_bf16(af[kf], hbf[1][kf], acc1, 0, 0, 0);
        }
        #pragma unroll
        for (int reg = 0; reg < 4; ++reg) {
            GHs[mt * 16 + quad * 4 + reg][l15]      = acc0[reg];
            GHs[mt * 16 + quad * 4 + reg][16 + l15] = acc1[reg];
        }
    }
    __syncthreads();

    // ---- gate update: 19 j-pairs x 32 mols = 608 items ----
    #pragma unroll
    for (int p = 0; p < 3; ++p) {
        const int idx = tid + p * 256;
        if (idx < 19 * 32) {
            const int mol = idx / 19, jp = idx - mol * 19;
            const int jl = jp * 2, jg = slice * GSL + jl;
            if (jg < 300) {
                const float hr0 = GHs[jl][mol],          hr1 = GHs[jl + 1][mol];
                const float hz0 = GHs[GSL + jl][mol],    hz1 = GHs[GSL + jl + 1][mol];
                const float hn0 = GHs[2 * GSL + jl][mol], hn1 = GHs[2 * GSL + jl + 1][mol];
                const bf16* girow = gi + ((long)(m0 + mol) * Aat + a) * 900;
                const uint gr = *(const uint*)(girow + jg);
                const uint gz = *(const uint*)(girow + 300 + jg);
                const uint gn = *(const uint*)(girow + 600 + jg);
                const float2 br = *(const float2*)(bhh + jg);
                const float2 bz = *(const float2*)(bhh + 300 + jg);
                const float2 bn = *(const float2*)(bhh + 600 + jg);
                float* hop = hfd + (long)(m0 + mol) * 320 + jg;
                const float2 hold = *(const float2*)hop;
                float hnew[2];
                #pragma unroll
                for (int j = 0; j < 2; ++j) {
                    const float ir  = j ? bhi(gr) : blo(gr);
                    const float iz  = j ? bhi(gz) : blo(gz);
                    const float inn = j ? bhi(gn) : blo(gn);
                    const float ghr = j ? hr1 + br.y : hr0 + br.x;
                    const float ghz = j ? hz1 + bz.y : hz0 + bz.x;
                    const float ghn = j ? hn1 + bn.y : hn0 + bn.x;
                    const float rr = 1.f / (1.f + __expf(-(ir + ghr)));
                    const float zz = 1.f / (1.f + __expf(-(iz + ghz)));
                    float nin = inn + rr * ghn;
                    nin = fminf(fmaxf(nin, -15.f), 15.f);
                    const float e2 = __expf(-2.f * nin);
                    const float nnv = (1.f - e2) / (1.f + e2);
                    hnew[j] = (1.f - zz) * nnv + zz * (j ? hold.y : hold.x);
                }
                const uint pk2 = f2bu(hnew[0]) | (f2bu(hnew[1]) << 16);
                *(float2*)hop = make_float2(hnew[0], hnew[1]);
                *(uint*)(hbw + (long)(m0 + mol) * 320 + jg) = pk2;
                *(uint*)(out + ((long)(m0 + mol) * Aat + a) * 600 + (long)dir * 300 + jg) = pk2;
            }
        }
    }
}

// =====================================================================
extern "C" void kernel_launch(void* const* d_in, const int* in_sizes, int n_in,
                              void* d_out, int out_size, void* d_ws, size_t ws_size,
                              hipStream_t stream)
{
    (void)in_sizes; (void)n_in; (void)out_size; (void)ws_size;

    const float* f_atoms  = (const float*)d_in[0];
    const float* f_bonds  = (const float*)d_in[1];
    const int*   a2b      = (const int*)d_in[2];
    const int*   b2a      = (const int*)d_in[3];
    const int*   b2revb   = (const int*)d_in[4];
    const float* W_i_atom = (const float*)d_in[7];
    const float* W_i_bond = (const float*)d_in[8];
    const float* W_h      = (const float*)d_in[9];
    const float* lr_W     = (const float*)d_in[10];
    const float* W_o_W    = (const float*)d_in[11];
    const float* W_o_b    = (const float*)d_in[12];
    const float* gWih_f   = (const float*)d_in[13];
    const float* gWhh_f   = (const float*)d_in[14];
    const float* gbih_f   = (const float*)d_in[15];
    const float* gbhh_f   = (const float*)d_in[16];
    const float* gWih_b   = (const float*)d_in[17];
    const float* gWhh_b   = (const float*)d_in[18];
    const float* gbih_b   = (const float*)d_in[19];
    const float* gbhh_b   = (const float*)d_in[20];

    // ---- workspace: same 4-region footprint as proven R6-R8 (~235.9 MB) ----
    const size_t F32A_B = (size_t)NP1 * Hd * 4;      // 39.32 MB
    const size_t BND_B  = (size_t)BP1 * Hd * 2;      // 78.64 MB
    const size_t H0_B   = (size_t)Mmol * Hd * 4;     // 614,400 B
    const size_t WPM_B  = (size_t)8 * 128 * 320 * 2; // 655,360 B (strip layout)

    size_t off = 0;
    auto alloc = [&](size_t b) { size_t r = off; off += (b + 255) & ~(size_t)255; return r; };
    const size_t r1_o = alloc(F32A_B);       // IA [1-7] -> {H0,strips,NRb,h} [8-12] -> AH [13-14]
    const size_t r2_o = alloc(F32A_B);       // MA [3-7] -> GRU [12-13]
    const size_t r3_o = alloc(BND_B);        // IB/MB1 [2-7] -> NODE [8-9] -> GIF [10-12]
    const size_t r4_o = alloc(BND_B + 4096); // FB16 [1b-2] -> MB0 [4-6] -> CC [7-8] -> GIB [11-12]

    char* ws = (char*)d_ws;
    float* IA   = (float*)(ws + r1_o);
    float* H0p  = (float*)(ws + r1_o);
    bf16*  WPmf = (bf16*)(ws + r1_o + ((H0_B + 255) & ~(size_t)255));
    bf16*  WPmb = (bf16*)((char*)WPmf + ((WPM_B + 255) & ~(size_t)255));
    bf16*  NRb  = (bf16*)(ws + r1_o + (2u << 20));   // +2MB, 19.66MB used
    float* Hf32 = (float*)(ws + r1_o + (23u << 20)); // 1.31MB  [2dir][512][320] f32
    bf16*  Hb16 = (bf16*)(ws + r1_o + (25u << 20));  // 1.31MB  [2buf][2dir][512][320] bf16
    float* AH   = (float*)(ws + r1_o);
    float* MAb  = (float*)(ws + r2_o);
    bf16*  GRU  = (bf16*)(ws + r2_o);
    bf16*  IB   = (bf16*)(ws + r3_o);
    bf16*  MB1  = IB;
    float* NODE = (float*)(ws + r3_o);
    bf16*  GIF  = (bf16*)(ws + r3_o);
    bf16*  FB16 = (bf16*)(ws + r4_o);
    bf16*  MB0  = (bf16*)(ws + r4_o);
    bf16*  CC   = (bf16*)(ws + r4_o);
    bf16*  GIB  = (bf16*)(ws + r4_o);
    float* OUT  = (float*)d_out;
    bf16*  WSC  = (bf16*)d_out;        // 614,400 B time-shared packed-weight scratch

    const dim3 blk(256);
    // R5: 1-D XCD-chunked grids (pad to multiple of 8; kernels decode+guard)
    auto grdM = [](int n, int h) {
        long J = (long)((h + 63) / 64) * ((n + 127) / 128);
        return dim3((unsigned)((J + 7) / 8 * 8));
    };
    auto grdF = [](int n, int h) {
        long J = (long)((h + BNc - 1) / BNc) * ((n + BMr - 1) / BMr);
        return dim3((unsigned)((J + 7) / 8 * 8));
    };
    auto pk = [&](const float* W, bf16* Wp, int h, int K, long hp, int Kp) {
        const long tot = hp * Kp;
        pack_w<<<dim3((tot + 255) / 256), blk, 0, stream>>>(W, Wp, h, K, tot, Kp);
    };

    // 1. IA = relu(f_atoms @ W_i_atom^T) -> f32 (VALU, full precision)
    gemm_ia<<<grdF(NP1, Hd), blk, 0, stream>>>(f_atoms, W_i_atom, IA, NP1, AF, Hd);
    // 1b. pack f_bonds -> bf16 [BP1][160]; W_i_bond -> [320][160] @d_out
    pk(f_bonds, FB16, BP1, BFd, BP1, 160);
    pk(W_i_bond, WSC, Hd, BFd, 320, 160);
    // 2. IB = relu(FB16 @ WIB^T)   [MFMA]
    mgemm<0, true, false, false, true, false, 0><<<grdM(BP1, Hd), blk, 0, stream>>>(
        FB16, nullptr, nullptr, nullptr, nullptr, WSC, nullptr, nullptr,
        IB, nullptr, BP1, 160, 160, Hd);
    // 3. MA = IA + sum*max(IB gathered)
    agg_kernel<true><<<NP1, 320, 0, stream>>>(IB, a2b, IA, MAb, 0);
    pk(W_h, WSC, Hd, Hd, 320, 320);
    // 4. MB0 = relu(IB + (MA[b2a]-IB[b2revb]) @ Wh0^T)   [MFMA fused gather]
    mgemm<3, true, false, true, true, false, 12><<<grdM(BP1, Hd), blk, 0, stream>>>(
        nullptr, MAb, IB, b2a, b2revb, WSC, nullptr, IB,
        MB0, nullptr, BP1, Hd, 320, Hd);
    // 5. MA += sum*max(MB0 gathered)
    agg_kernel<true><<<NP1, 320, 0, stream>>>(MB0, a2b, MAb, MAb, 0);
    pk(W_h + 300 * 300, WSC, Hd, Hd, 320, 320);
    // 6. MB1(=IB) = relu(IB + (MA[b2a]-MB0[b2revb]) @ Wh1^T)
    mgemm<3, true, false, true, true, false, 12><<<grdM(BP1, Hd), blk, 0, stream>>>(
        nullptr, MAb, MB0, b2a, b2revb, WSC, nullptr, IB,
        MB1, nullptr, BP1, Hd, 320, Hd);
    // 7. CC = concat3 bf16 (agg(MB1) | MA | IA), segment-padded to 960
    cc_build<<<Nat, 320, 0, stream>>>(MB1, a2b, MAb, IA, CC);
    pack_lrw<<<(320 * 960 + 255) / 256, blk, 0, stream>>>(lr_W, WSC);
    // 8. node = CC @ lrWp^T -> NODE f32 (pre-relu) + NRb bf16 (relu)  [MFMA]
    mgemm<0, false, false, false, false, true, 0><<<grdM(Nat, Hd), blk, 0, stream>>>(
        CC, nullptr, nullptr, nullptr, nullptr, WSC, nullptr, nullptr,
        NODE, NRb, Nat, 960, 960, Hd);
    // 9. h0 + GRU Whh slice-strips (r1: IA dead)
    h0_kernel<<<Mmol, 320, 0, stream>>>(NODE, H0p);
    {
        const int tot = 8 * 128 * 320;
        pack_gws<<<dim3((tot + 255) / 256), blk, 0, stream>>>(gWhh_f, WPmf);
        pack_gws<<<dim3((tot + 255) / 256), blk, 0, stream>>>(gWhh_b, WPmb);
    }
    // 10. GIF = NRb @ gWih_f^T + gbih_f   [MFMA]
    pk(gWih_f, WSC, 900, Hd, 960, 320);
    mgemm<0, false, true, false, true, false, 12><<<grdM(Nat, 900), blk, 0, stream>>>(
        NRb, nullptr, nullptr, nullptr, nullptr, WSC, gbih_f, nullptr,
        GIF, nullptr, Nat, Hd, 320, 900);
    // 11. GIB likewise
    pk(gWih_b, WSC, 900, Hd, 960, 320);
    mgemm<0, false, true, false, true, false, 12><<<grdM(Nat, 900), blk, 0, stream>>>(
        NRb, nullptr, nullptr, nullptr, nullptr, WSC, gbih_b, nullptr,
        GIB, nullptr, Nat, Hd, 320, 900);
    // 12. GRU: h init + 64 step-kernels (kernel boundary = global sync)
    hinit_kernel<<<dim3(Mmol, 2), 320, 0, stream>>>(H0p, Hf32, Hb16);
    for (int t = 0; t < Aat; ++t)
        gru_step<<<dim3(256), blk, 0, stream>>>(
            GIF, GIB, WPmf, WPmb, gbhh_f, gbhh_b, Hf32, Hb16, GRU, t, 0);
    // 13. AH = relu(GRU @ W_o_W^T + W_o_b)   [MFMA]
    pk(W_o_W, WSC, Hd, 600, 320, 608);
    mgemm<0, true, true, false, false, false, 24><<<grdM(Nat, Hd), blk, 0, stream>>>(
        GRU, nullptr, nullptr, nullptr, nullptr, WSC, W_o_b, nullptr,
        AH, nullptr, Nat, 600, 608, Hd);
    // 14. mol_vecs = mean -> d_out
    mean_kernel<<<Mmol, 320, 0, stream>>>(AH, OUT);
}

// Round 11
// 1883.206 us; speedup vs baseline: 2.0405x; 1.0290x over previous
//
#include <hip/hip_runtime.h>
#include <hip/hip_bf16.h>

using bf16 = __hip_bfloat16;
using uint = unsigned int;
typedef __attribute__((ext_vector_type(8))) short short8v;   // 8 x bf16 MFMA operand
typedef __attribute__((ext_vector_type(4))) float float4v;   // MFMA accumulator

__device__ __forceinline__ float b2f(bf16 x){ return __bfloat162float(x); }
__device__ __forceinline__ bf16  f2b(float x){ return __float2bfloat16(x); }
__device__ __forceinline__ uint f2bu(float x){            // bf16 bits, RNE
    uint u = __float_as_uint(x);
    return (u + 0x7fffu + ((u >> 16) & 1u)) >> 16;
}
__device__ __forceinline__ float blo(uint u){ return __uint_as_float(u << 16); }
__device__ __forceinline__ float bhi(uint u){ return __uint_as_float(u & 0xffff0000u); }

// ---------------- problem constants ----------------
constexpr int Mmol = 512, Aat = 64;
constexpr int Nat  = Mmol * Aat;      // 32768
constexpr int NP1  = Nat + 1;
constexpr int Bnd  = Nat * 4;         // 131072
constexpr int BP1  = Bnd + 1;
constexpr int Hd   = 300;
constexpr int AF   = 133, BFd = 147;
constexpr int NB   = 6;
constexpr int GSL  = 38;              // h-elems per GRU slice (8 x 38 = 304 >= 300)

// =====================================================================
// MFMA GEMM: C[n,h] = act( A[n,K] @ Wp[h,Kp]^T (+bias)(+res) )
// R5 form — MEASURED OPTIMUM (226us, 56 VGPR, occupancy 41%):
//   1-D grid + chunked XCD-bijective remap (A-side fetched once/XCD;
//   col-tiles of a row-tile run back-to-back on one XCD's L2).
// Pipelining attempts REJECTED by measurement:
//   R6 struct-pipeline -> scratch spill (WRITE 81->237MB, +20%).
//   R9 flat-array pipeline -> VGPR 56->96 crossed the 64-VGPR
//   occupancy boundary (waves/SIMD 8->4, occupancy 41->21.6%, +15%).
// Serial k-loop + max TLP wins for this latency-bound gather GEMM.
// =====================================================================
template<int AM, bool RELU, bool BIAS, bool RES, bool OUTBF16, bool DUAL, int TAILK>
__global__ __launch_bounds__(256) void mgemm(
    const bf16* __restrict__ Abh, const float* __restrict__ MAf, const bf16* __restrict__ MBh,
    const int* __restrict__ g1, const int* __restrict__ g2,
    const bf16* __restrict__ Wp, const float* __restrict__ bias, const bf16* __restrict__ res,
    void* __restrict__ Cp, bf16* __restrict__ Cp2, int n, int K, int Kp, int h)
{
    const int  NX = (h + 63) >> 6;
    const long NY = ((long)n + 127) >> 7;
    const long J  = (long)NX * NY;
    const long job = (long)(blockIdx.x & 7) * (gridDim.x >> 3) + (blockIdx.x >> 3);
    if (job >= J) return;                       // block-uniform, no barriers
    const int  bx = (int)(job % NX);
    const long by = job / NX;
    const long rowBase = by * 128;
    const long colBase = (long)bx * 64;

    const int tid  = threadIdx.x;
    const int lane = tid & 63, w = tid >> 6;
    const int l15  = lane & 15, quad = lane >> 4;

    long arow[2], ga[2], gb[2];
    #pragma unroll
    for (int mt = 0; mt < 2; ++mt) {
        long r = rowBase + w * 32 + mt * 16 + l15;
        if (r >= n) r = n - 1;               // clamped rows: garbage acc, never stored
        arow[mt] = r;
        if constexpr (AM == 3) { ga[mt] = g1[r]; gb[mt] = g2[r]; }
        else { ga[mt] = 0; gb[mt] = 0; }
    }

    const bf16* wp0 = Wp + (colBase + l15) * (long)Kp + quad * 8;

    float4v acc[2][4];
    #pragma unroll
    for (int mt = 0; mt < 2; ++mt)
        #pragma unroll
        for (int nt = 0; nt < 4; ++nt)
            acc[mt][nt] = (float4v){0.f, 0.f, 0.f, 0.f};

    const int ktiles = (K + 31) / 32;
    for (int kt = 0; kt < ktiles; ++kt) {
        const int kb = kt * 32;
        const int koff = kb + quad * 8;
        short8v bfr[4];
        #pragma unroll
        for (int nt = 0; nt < 4; ++nt)
            bfr[nt] = *(const short8v*)(wp0 + (long)nt * 16 * Kp + kb);
        short8v af[2];
        if constexpr (AM == 0) {
            #pragma unroll
            for (int mt = 0; mt < 2; ++mt) {
                const bf16* p = Abh + arow[mt] * (long)K + koff;
                union { uint2 u2[2]; short8v s; } t;
                t.u2[0] = *(const uint2*)p;
                t.u2[1] = *(const uint2*)(p + 4);
                af[mt] = t.s;
            }
        } else {   // AM == 3 fused gather-sub
            #pragma unroll
            for (int mt = 0; mt < 2; ++mt) {
                const float* pa = MAf + ga[mt] * 300 + koff;
                const bf16*  pb = MBh + gb[mt] * 300 + koff;
                const float4 m0 = *(const float4*)pa;
                const float4 m1 = *(const float4*)(pa + 4);
                const uint2  u0 = *(const uint2*)pb;
                const uint2  u1 = *(const uint2*)(pb + 4);
                float v[8];
                v[0] = m0.x - blo(u0.x); v[1] = m0.y - bhi(u0.x);
                v[2] = m0.z - blo(u0.y); v[3] = m0.w - bhi(u0.y);
                v[4] = m1.x - blo(u1.x); v[5] = m1.y - bhi(u1.x);
                v[6] = m1.z - blo(u1.y); v[7] = m1.w - bhi(u1.y);
                short8v s;
                #pragma unroll
                for (int j = 0; j < 8; ++j) s[j] = (short)f2bu(v[j]);
                af[mt] = s;
            }
        }
        if constexpr (TAILK != 0) {
            if (kb + 32 > K) {               // uniform branch, last tile only
                #pragma unroll
                for (int j = 0; j < 8; ++j)
                    if (koff + j >= K) { af[0][j] = 0; af[1][j] = 0; }
            }
        }
        #pragma unroll
        for (int mt = 0; mt < 2; ++mt)
            #pragma unroll
            for (int nt = 0; nt < 4; ++nt)
                acc[mt][nt] = __builtin_amdgcn_mfma_f32_16x16x32_bf16(
                    af[mt], bfr[nt], acc[mt][nt], 0, 0, 0);
    }

    float biasv[4];
    #pragma unroll
    for (int nt = 0; nt < 4; ++nt) {
        const long c = colBase + nt * 16 + l15;
        biasv[nt] = (BIAS && c < h) ? bias[c] : 0.f;
    }
    #pragma unroll
    for (int mt = 0; mt < 2; ++mt) {
        #pragma unroll
        for (int reg = 0; reg < 4; ++reg) {
            const long r = rowBase + w * 32 + mt * 16 + quad * 4 + reg;
            if (r < n) {
                #pragma unroll
                for (int nt = 0; nt < 4; ++nt) {
                    const long c = colBase + nt * 16 + l15;
                    if (c < h) {
                        float v = acc[mt][nt][reg];
                        if constexpr (RES)  v += b2f(res[r * (long)h + c]);
                        if constexpr (BIAS) v += biasv[nt];
                        if constexpr (RELU) v = fmaxf(v, 0.f);
                        if constexpr (DUAL) {
                            ((float*)Cp)[r * (long)h + c] = v;
                            Cp2[r * (long)h + c] = f2b(fmaxf(v, 0.f));
                        } else if constexpr (OUTBF16) {
                            ((bf16*)Cp)[r * (long)h + c] = f2b(v);
                        } else {
                            ((float*)Cp)[r * (long)h + c] = v;
                        }
                    }
                }
            }
        }
    }
}

// =====================================================================
__global__ __launch_bounds__(256) void pack_w(const float* __restrict__ W, bf16* __restrict__ Wp,
                                              int h, int K, long total, int Kp)
{
    const long idx = (long)blockIdx.x * 256 + threadIdx.x;
    if (idx >= total) return;
    const long r = idx / Kp;
    const int kk = (int)(idx - r * Kp);
    Wp[idx] = (r < h && kk < K) ? f2b(W[r * (long)K + kk]) : f2b(0.f);
}

// lr_W [300][900] -> Wp [320][960] bf16, segment-padded (3 x 300->320)
__global__ __launch_bounds__(256) void pack_lrw(const float* __restrict__ W, bf16* __restrict__ Wp)
{
    const int idx = blockIdx.x * 256 + threadIdx.x;
    if (idx >= 320 * 960) return;
    const int r = idx / 960, c = idx - r * 960;
    const int seg = c / 320, kk = c - seg * 320;
    Wp[idx] = (r < 300 && kk < 300) ? f2b(W[r * 900 + seg * 300 + kk]) : f2b(0.f);
}

// pack_gws: gWhh [900][300] f32 -> 8 slice-strips [8][128][320] bf16.
// Strip s row r (r = g*38 + l, g=gate 0..2): W row g*300 + (s*38 + l).
// Rows >=114, j>=300 and k>=300 are zero (K-pad makes h pad cols harmless).
__global__ __launch_bounds__(256) void pack_gws(const float* __restrict__ W, bf16* __restrict__ Wp)
{
    const int idx = blockIdx.x * 256 + threadIdx.x;
    if (idx >= 8 * 128 * 320) return;
    const int k = idx % 320;
    const int r = (idx / 320) & 127;
    const int s = idx / (320 * 128);
    const int g = r / GSL, l = r - g * GSL;
    const int j = s * GSL + l;
    bf16 v = f2b(0.f);
    if (r < 114 && j < 300 && k < 300)
        v = f2b(W[(g * 300 + j) * 300 + k]);
    Wp[idx] = v;
}

// =====================================================================
// f32 VALU GEMM (IA only, k=133; keeps f_atoms at full precision)
// R5: chunked XCD remap (col-tiles of one row-stripe on one XCD).
// =====================================================================
constexpr int BMr = 256, BNc = 64;

__global__ __launch_bounds__(256) void gemm_ia(
    const float* __restrict__ A, const float* __restrict__ W,
    float* __restrict__ Cp, int n, int k, int h)
{
    __shared__ float As[16][BMr];
    __shared__ float Ws[16][BNc];

    const int  NC = (h + BNc - 1) / BNc;
    const long NR = ((long)n + BMr - 1) / BMr;
    const long J  = (long)NC * NR;
    const long job = (long)(blockIdx.x & 7) * (gridDim.x >> 3) + (blockIdx.x >> 3);
    if (job >= J) return;                       // block-uniform, before barriers
    const int  c0 = (int)(job % NC);
    const long rt = job / NC;
    const long rowBase = rt * BMr;
    const long colBase = (long)c0 * BNc;

    const int tid = threadIdx.x;
    const int tx = tid & 7, ty = tid >> 3;

    const long grow = rowBase + tid;
    const bool rv = grow < n;
    const int wcol = tid & 63, kq = tid >> 6;
    const long gcol = colBase + wcol;
    const bool cvv = gcol < h;

    float acc[8][8] = {};

    const int ktiles = (k + 15) / 16;
    for (int kt = 0; kt < ktiles; ++kt) {
        const int kb = kt * 16;
        __syncthreads();
        const float* ap = A + grow * (long)k + kb;
        #pragma unroll
        for (int c = 0; c < 16; ++c)
            As[c][tid] = (rv && kb + c < k) ? ap[c] : 0.f;
        #pragma unroll
        for (int c = 0; c < 4; ++c) {
            const int kk = kb + kq * 4 + c;
            Ws[kq * 4 + c][wcol] = (cvv && kk < k) ? W[gcol * (long)k + kk] : 0.f;
        }
        __syncthreads();
        #pragma unroll
        for (int kk = 0; kk < 16; ++kk) {
            const float4 a0 = *(const float4*)&As[kk][ty * 8];
            const float4 a1 = *(const float4*)&As[kk][ty * 8 + 4];
            const float4 b0 = *(const float4*)&Ws[kk][tx * 8];
            const float4 b1 = *(const float4*)&Ws[kk][tx * 8 + 4];
            const float aa[8] = {a0.x,a0.y,a0.z,a0.w,a1.x,a1.y,a1.z,a1.w};
            const float bb[8] = {b0.x,b0.y,b0.z,b0.w,b1.x,b1.y,b1.z,b1.w};
            #pragma unroll
            for (int i = 0; i < 8; ++i)
                #pragma unroll
                for (int j = 0; j < 8; ++j)
                    acc[i][j] = fmaf(aa[i], bb[j], acc[i][j]);
        }
    }
    #pragma unroll
    for (int i = 0; i < 8; ++i) {
        const long r = rowBase + ty * 8 + i;
        if (r < n) {
            #pragma unroll
            for (int j = 0; j < 8; ++j) {
                const long c = colBase + tx * 8 + j;
                if (c < h) Cp[r * (long)h + c] = fmaxf(acc[i][j], 0.f);
            }
        }
    }
}

// =====================================================================
template<bool ADD>
__global__ __launch_bounds__(320) void agg_kernel(
    const bf16* __restrict__ MB, const int* __restrict__ a2b,
    const float* __restrict__ src, float* __restrict__ out, int rowoff)
{
    const int hh = threadIdx.x;
    if (hh >= Hd) return;
    const long atom = (long)blockIdx.x + rowoff;
    const int* nb = a2b + atom * NB;
    float s = 0.f, mx = -1e30f;
    #pragma unroll
    for (int j = 0; j < NB; ++j) {
        const float v = b2f(MB[(long)nb[j] * Hd + hh]);
        s += v; mx = fmaxf(mx, v);
    }
    const float agg = s * mx;
    const long o = (long)blockIdx.x * Hd + hh;
    if constexpr (ADD) out[o] = src[atom * Hd + hh] + agg;
    else               out[o] = agg;
}

// cc_build: CC[r][0:300)=sum*max(MB1 gather), [320:620)=MA, [640:940)=IA, pads 0
__global__ __launch_bounds__(320) void cc_build(
    const bf16* __restrict__ MB, const int* __restrict__ a2b,
    const float* __restrict__ MA, const float* __restrict__ IA,
    bf16* __restrict__ CC)
{
    const int hh = threadIdx.x;
    const long r = blockIdx.x;          // 0..Nat-1, atom = r+1
    bf16* cr = CC + r * 960;
    if (hh < Hd) {
        const long atom = r + 1;
        const int* nb = a2b + atom * NB;
        float s = 0.f, mx = -1e30f;
        #pragma unroll
        for (int j = 0; j < NB; ++j) {
            const float v = b2f(MB[(long)nb[j] * Hd + hh]);
            s += v; mx = fmaxf(mx, v);
        }
        cr[hh]       = f2b(s * mx);
        cr[320 + hh] = f2b(MA[atom * Hd + hh]);
        cr[640 + hh] = f2b(IA[atom * Hd + hh]);
    } else {
        const int p = hh - Hd;          // 0..19
        cr[300 + p] = f2b(0.f);
        cr[620 + p] = f2b(0.f);
        cr[940 + p] = f2b(0.f);
    }
}

__global__ __launch_bounds__(320) void h0_kernel(const float* __restrict__ node, float* __restrict__ h0)
{
    const int hh = threadIdx.x;
    if (hh >= Hd) return;
    const long m = blockIdx.x;
    float mx = -1e30f;
    for (int a = 0; a < Aat; ++a)
        mx = fmaxf(mx, node[(m * Aat + a) * (long)Hd + hh]);
    h0[m * Hd + hh] = mx;
}

__global__ __launch_bounds__(320) void mean_kernel(const float* __restrict__ AH, float* __restrict__ out)
{
    const int hh = threadIdx.x;
    if (hh >= Hd) return;
    const long m = blockIdx.x;
    float s = 0.f;
    for (int a = 0; a < Aat; ++a)
        s += AH[(m * Aat + a) * (long)Hd + hh];
    out[m * Hd + hh] = s * (1.f / 64.f);
}

// =====================================================================
// hinit: h0 f32 [512][300] -> h_f32 [2dir][512][320] + h_bf16 buf0;
// buf1 zeroed. Pads (j>=300) zero.
// =====================================================================
__global__ __launch_bounds__(320) void hinit_kernel(const float* __restrict__ h0,
                                                    float* __restrict__ hf, bf16* __restrict__ hb)
{
    const int j = threadIdx.x;           // 0..319
    const long m = blockIdx.x;
    const int dir = blockIdx.y;
    const float v = (j < 300) ? h0[m * 300 + j] : 0.f;
    hf[((long)dir * 512 + m) * 320 + j] = v;
    hb[((long)dir * 512 + m) * 320 + j] = f2b(v);                    // buf 0
    hb[((long)(2 + dir) * 512 + m) * 320 + j] = f2b(0.f);            // buf 1
}

// =====================================================================
// gru_step: one GRU timestep for ALL mols/dirs (R4/R5 proven, 8.9us/step
// incl. launch). R7 coop-launch and R8 software-barrier persistent
// variants both refuted (container kill / 39us-per-step fence cost);
// kernel-boundary sync is the measured optimum for this decomposition.
// Slice layout pins each (slice,dir) W-strip to one XCD (slice =
// blockIdx&7 = XCD lane): 164KB hot set per XCD, fully L2-resident.
// =====================================================================
__global__ __launch_bounds__(256) void gru_step(
    const bf16* __restrict__ gi_f, const bf16* __restrict__ gi_b,
    const bf16* __restrict__ wsf, const bf16* __restrict__ wsb,   // [8][128][320]
    const float* __restrict__ bhh_f, const float* __restrict__ bhh_b,
    float* __restrict__ hf, bf16* __restrict__ hb, bf16* __restrict__ out,
    int t, int force)
{
    const int slice = blockIdx.x & 7;
    const int dir   = (blockIdx.x >> 3) & 1;
    const int m0    = (blockIdx.x >> 4) * 32;
    const int a     = dir ? (Aat - 1 - t) : t;

    const bf16*  WS  = (dir ? wsb : wsf) + (long)slice * 128 * 320;
    const bf16*  gi  = dir ? gi_b : gi_f;
    const float* bhh = dir ? bhh_b : bhh_f;
    float* hfd = hf + (long)dir * 512 * 320;
    const int par = t & 1;
    const bf16* hbr = hb + ((long)(par * 2 + dir) * 512) * 320;
    bf16*       hbw = hb + ((long)(((t + 1) & 1) * 2 + dir) * 512) * 320;

    __shared__ float GHs[128][36];      // gh staging [Wrow][mol], pad 36
    __shared__ uint  Hs[32][164];       // h tile [mol][160 uints], pad 164
    __shared__ float ldspad[12288];     // 48KB pad -> ~88KB total -> 1 block/CU

    const int tid  = threadIdx.x;
    const int lane = tid & 63, w = tid >> 6;     // w: 0..3
    const int l15  = lane & 15, quad = lane >> 4;

    if (force) {                        // never taken; keeps ldspad allocated
        ldspad[tid] = (float)tid;
        GHs[0][0] = ldspad[(tid + force) & 4095];
    }

    // ---- stage h tile (32 mols x 320 elems bf16) into LDS, coalesced ----
    #pragma unroll
    for (int q = 0; q < 10; ++q) {
        const int idx = tid + q * 256;            // 0..2559
        const int row = idx / 80, c = idx - row * 80;
        const uint2 v = *(const uint2*)(hbr + (long)(m0 + row) * 320 + c * 4);
        *(uint2*)&Hs[row][c * 2] = v;
    }
    __syncthreads();

    // ---- B fragments (h) from LDS ----
    short8v hbf[2][10];
    #pragma unroll
    for (int ct = 0; ct < 2; ++ct)
        #pragma unroll
        for (int kf = 0; kf < 10; ++kf)
            hbf[ct][kf] = *(const short8v*)&Hs[ct * 16 + l15][kf * 16 + quad * 4];

    // ---- MFMA: gh_strip = W_strip @ h  (2 M-tiles/wave x 2 col-tiles) ----
    #pragma unroll
    for (int mti = 0; mti < 2; ++mti) {
        const int mt = w + mti * 4;
        const bf16* ap = WS + (long)(mt * 16 + l15) * 320 + quad * 8;
        short8v af[10];
        #pragma unroll
        for (int kf = 0; kf < 10; ++kf)
            af[kf] = *(const short8v*)(ap + kf * 32);
        float4v acc0 = (float4v){0.f, 0.f, 0.f, 0.f};
        float4v acc1 = (float4v){0.f, 0.f, 0.f, 0.f};
        #pragma unroll
        for (int kf = 0; kf < 10; ++kf) {
            acc0 = __builtin_amdgcn_mfma_f32_16x16x32_bf16(af[kf], hbf[0][kf], acc0, 0, 0, 0);
            acc1 = __builtin_amdgcn_mfma_f32_16x16x32_bf16(af[kf], hbf[1][kf], acc1, 0, 0, 0);
        }
        #pragma unroll
        for (int reg = 0; reg < 4; ++reg) {
            GHs[mt * 16 + quad * 4 + reg][l15]      = acc0[reg];
            GHs[mt * 16 + quad * 4 + reg][16 + l15] = acc1[reg];
        }
    }
    __syncthreads();

    // ---- gate update: 19 j-pairs x 32 mols = 608 items ----
    #pragma unroll
    for (int p = 0; p < 3; ++p) {
        const int idx = tid + p * 256;
        if (idx < 19 * 32) {
            const int mol = idx / 19, jp = idx - mol * 19;
            const int jl = jp * 2, jg = slice * GSL + jl;
            if (jg < 300) {
                const float hr0 = GHs[jl][mol],          hr1 = GHs[jl + 1][mol];
                const float hz0 = GHs[GSL + jl][mol],    hz1 = GHs[GSL + jl + 1][mol];
                const float hn0 = GHs[2 * GSL + jl][mol], hn1 = GHs[2 * GSL + jl + 1][mol];
                const bf16* girow = gi + ((long)(m0 + mol) * Aat + a) * 900;
                const uint gr = *(const uint*)(girow + jg);
                const uint gz = *(const uint*)(girow + 300 + jg);
                const uint gn = *(const uint*)(girow + 600 + jg);
                const float2 br = *(const float2*)(bhh + jg);
                const float2 bz = *(const float2*)(bhh + 300 + jg);
                const float2 bn = *(const float2*)(bhh + 600 + jg);
                float* hop = hfd + (long)(m0 + mol) * 320 + jg;
                const float2 hold = *(const float2*)hop;
                float hnew[2];
                #pragma unroll
                for (int j = 0; j < 2; ++j) {
                    const float ir  = j ? bhi(gr) : blo(gr);
                    const float iz  = j ? bhi(gz) : blo(gz);
                    const float inn = j ? bhi(gn) : blo(gn);
                    const float ghr = j ? hr1 + br.y : hr0 + br.x;
                    const float ghz = j ? hz1 + bz.y : hz0 + bz.x;
                    const float ghn = j ? hn1 + bn.y : hn0 + bn.x;
                    const float rr = 1.f / (1.f + __expf(-(ir + ghr)));
                    const float zz = 1.f / (1.f + __expf(-(iz + ghz)));
                    float nin = inn + rr * ghn;
                    nin = fminf(fmaxf(nin, -15.f), 15.f);
                    const float e2 = __expf(-2.f * nin);
                    const float nnv = (1.f - e2) / (1.f + e2);
                    hnew[j] = (1.f - zz) * nnv + zz * (j ? hold.y : hold.x);
                }
                const uint pk2 = f2bu(hnew[0]) | (f2bu(hnew[1]) << 16);
                *(float2*)hop = make_float2(hnew[0], hnew[1]);
                *(uint*)(hbw + (long)(m0 + mol) * 320 + jg) = pk2;
                *(uint*)(out + ((long)(m0 + mol) * Aat + a) * 600 + (long)dir * 300 + jg) = pk2;
            }
        }
    }
}

// =====================================================================
extern "C" void kernel_launch(void* const* d_in, const int* in_sizes, int n_in,
                              void* d_out, int out_size, void* d_ws, size_t ws_size,
                              hipStream_t stream)
{
    (void)in_sizes; (void)n_in; (void)out_size; (void)ws_size;

    const float* f_atoms  = (const float*)d_in[0];
    const float* f_bonds  = (const float*)d_in[1];
    const int*   a2b      = (const int*)d_in[2];
    const int*   b2a      = (const int*)d_in[3];
    const int*   b2revb   = (const int*)d_in[4];
    const float* W_i_atom = (const float*)d_in[7];
    const float* W_i_bond = (const float*)d_in[8];
    const float* W_h      = (const float*)d_in[9];
    const float* lr_W     = (const float*)d_in[10];
    const float* W_o_W    = (const float*)d_in[11];
    const float* W_o_b    = (const float*)d_in[12];
    const float* gWih_f   = (const float*)d_in[13];
    const float* gWhh_f   = (const float*)d_in[14];
    const float* gbih_f   = (const float*)d_in[15];
    const float* gbhh_f   = (const float*)d_in[16];
    const float* gWih_b   = (const float*)d_in[17];
    const float* gWhh_b   = (const float*)d_in[18];
    const float* gbih_b   = (const float*)d_in[19];
    const float* gbhh_b   = (const float*)d_in[20];

    // ---- workspace: same 4-region footprint as proven R6-R8 (~235.9 MB) ----
    const size_t F32A_B = (size_t)NP1 * Hd * 4;      // 39.32 MB
    const size_t BND_B  = (size_t)BP1 * Hd * 2;      // 78.64 MB
    const size_t H0_B   = (size_t)Mmol * Hd * 4;     // 614,400 B
    const size_t WPM_B  = (size_t)8 * 128 * 320 * 2; // 655,360 B (strip layout)

    size_t off = 0;
    auto alloc = [&](size_t b) { size_t r = off; off += (b + 255) & ~(size_t)255; return r; };
    const size_t r1_o = alloc(F32A_B);       // IA [1-7] -> {H0,strips,NRb,h} [8-12] -> AH [13-14]
    const size_t r2_o = alloc(F32A_B);       // MA [3-7] -> GRU [12-13]
    const size_t r3_o = alloc(BND_B);        // IB/MB1 [2-7] -> NODE [8-9] -> GIF [10-12]
    const size_t r4_o = alloc(BND_B + 4096); // FB16 [1b-2] -> MB0 [4-6] -> CC [7-8] -> GIB [11-12]

    char* ws = (char*)d_ws;
    float* IA   = (float*)(ws + r1_o);
    float* H0p  = (float*)(ws + r1_o);
    bf16*  WPmf = (bf16*)(ws + r1_o + ((H0_B + 255) & ~(size_t)255));
    bf16*  WPmb = (bf16*)((char*)WPmf + ((WPM_B + 255) & ~(size_t)255));
    bf16*  NRb  = (bf16*)(ws + r1_o + (2u << 20));   // +2MB, 19.66MB used
    float* Hf32 = (float*)(ws + r1_o + (23u << 20)); // 1.31MB  [2dir][512][320] f32
    bf16*  Hb16 = (bf16*)(ws + r1_o + (25u << 20));  // 1.31MB  [2buf][2dir][512][320] bf16
    float* AH   = (float*)(ws + r1_o);
    float* MAb  = (float*)(ws + r2_o);
    bf16*  GRU  = (bf16*)(ws + r2_o);
    bf16*  IB   = (bf16*)(ws + r3_o);
    bf16*  MB1  = IB;
    float* NODE = (float*)(ws + r3_o);
    bf16*  GIF  = (bf16*)(ws + r3_o);
    bf16*  FB16 = (bf16*)(ws + r4_o);
    bf16*  MB0  = (bf16*)(ws + r4_o);
    bf16*  CC   = (bf16*)(ws + r4_o);
    bf16*  GIB  = (bf16*)(ws + r4_o);
    float* OUT  = (float*)d_out;
    bf16*  WSC  = (bf16*)d_out;        // 614,400 B time-shared packed-weight scratch

    const dim3 blk(256);
    // R5: 1-D XCD-chunked grids (pad to multiple of 8; kernels decode+guard)
    auto grdM = [](int n, int h) {
        long J = (long)((h + 63) / 64) * ((n + 127) / 128);
        return dim3((unsigned)((J + 7) / 8 * 8));
    };
    auto grdF = [](int n, int h) {
        long J = (long)((h + BNc - 1) / BNc) * ((n + BMr - 1) / BMr);
        return dim3((unsigned)((J + 7) / 8 * 8));
    };
    auto pk = [&](const float* W, bf16* Wp, int h, int K, long hp, int Kp) {
        const long tot = hp * Kp;
        pack_w<<<dim3((tot + 255) / 256), blk, 0, stream>>>(W, Wp, h, K, tot, Kp);
    };

    // 1. IA = relu(f_atoms @ W_i_atom^T) -> f32 (VALU, full precision)
    gemm_ia<<<grdF(NP1, Hd), blk, 0, stream>>>(f_atoms, W_i_atom, IA, NP1, AF, Hd);
    // 1b. pack f_bonds -> bf16 [BP1][160]; W_i_bond -> [320][160] @d_out
    pk(f_bonds, FB16, BP1, BFd, BP1, 160);
    pk(W_i_bond, WSC, Hd, BFd, 320, 160);
    // 2. IB = relu(FB16 @ WIB^T)   [MFMA]
    mgemm<0, true, false, false, true, false, 0><<<grdM(BP1, Hd), blk, 0, stream>>>(
        FB16, nullptr, nullptr, nullptr, nullptr, WSC, nullptr, nullptr,
        IB, nullptr, BP1, 160, 160, Hd);
    // 3. MA = IA + sum*max(IB gathered)
    agg_kernel<true><<<NP1, 320, 0, stream>>>(IB, a2b, IA, MAb, 0);
    pk(W_h, WSC, Hd, Hd, 320, 320);
    // 4. MB0 = relu(IB + (MA[b2a]-IB[b2revb]) @ Wh0^T)   [MFMA fused gather]
    mgemm<3, true, false, true, true, false, 12><<<grdM(BP1, Hd), blk, 0, stream>>>(
        nullptr, MAb, IB, b2a, b2revb, WSC, nullptr, IB,
        MB0, nullptr, BP1, Hd, 320, Hd);
    // 5. MA += sum*max(MB0 gathered)
    agg_kernel<true><<<NP1, 320, 0, stream>>>(MB0, a2b, MAb, MAb, 0);
    pk(W_h + 300 * 300, WSC, Hd, Hd, 320, 320);
    // 6. MB1(=IB) = relu(IB + (MA[b2a]-MB0[b2revb]) @ Wh1^T)
    mgemm<3, true, false, true, true, false, 12><<<grdM(BP1, Hd), blk, 0, stream>>>(
        nullptr, MAb, MB0, b2a, b2revb, WSC, nullptr, IB,
        MB1, nullptr, BP1, Hd, 320, Hd);
    // 7. CC = concat3 bf16 (agg(MB1) | MA | IA), segment-padded to 960
    cc_build<<<Nat, 320, 0, stream>>>(MB1, a2b, MAb, IA, CC);
    pack_lrw<<<(320 * 960 + 255) / 256, blk, 0, stream>>>(lr_W, WSC);
    // 8. node = CC @ lrWp^T -> NODE f32 (pre-relu) + NRb bf16 (relu)  [MFMA]
    mgemm<0, false, false, false, false, true, 0><<<grdM(Nat, Hd), blk, 0, stream>>>(
        CC, nullptr, nullptr, nullptr, nullptr, WSC, nullptr, nullptr,
        NODE, NRb, Nat, 960, 960, Hd);
    // 9. h0 + GRU Whh slice-strips (r1: IA dead)
    h0_kernel<<<Mmol, 320, 0, stream>>>(NODE, H0p);
    {
        const int tot = 8 * 128 * 320;
        pack_gws<<<dim3((tot + 255) / 256), blk, 0, stream>>>(gWhh_f, WPmf);
        pack_gws<<<dim3((tot + 255) / 256), blk, 0, stream>>>(gWhh_b, WPmb);
    }
    // 10. GIF = NRb @ gWih_f^T + gbih_f   [MFMA]
    pk(gWih_f, WSC, 900, Hd, 960, 320);
    mgemm<0, false, true, false, true, false, 12><<<grdM(Nat, 900), blk, 0, stream>>>(
        NRb, nullptr, nullptr, nullptr, nullptr, WSC, gbih_f, nullptr,
        GIF, nullptr, Nat, Hd, 320, 900);
    // 11. GIB likewise
    pk(gWih_b, WSC, 900, Hd, 960, 320);
    mgemm<0, false, true, false, true, false, 12><<<grdM(Nat, 900), blk, 0, stream>>>(
        NRb, nullptr, nullptr, nullptr, nullptr, WSC, gbih_b, nullptr,
        GIB, nullptr, Nat, Hd, 320, 900);
    // 12. GRU: h init + 64 step-kernels (kernel boundary = global sync)
    hinit_kernel<<<dim3(Mmol, 2), 320, 0, stream>>>(H0p, Hf32, Hb16);
    for (int t = 0; t < Aat; ++t)
        gru_step<<<dim3(256), blk, 0, stream>>>(
            GIF, GIB, WPmf, WPmb, gbhh_f, gbhh_b, Hf32, Hb16, GRU, t, 0);
    // 13. AH = relu(GRU @ W_o_W^T + W_o_b)   [MFMA]
    pk(W_o_W, WSC, Hd, 600, 320, 608);
    mgemm<0, true, true, false, false, false, 24><<<grdM(Nat, Hd), blk, 0, stream>>>(
        GRU, nullptr, nullptr, nullptr, nullptr, WSC, W_o_b, nullptr,
        AH, nullptr, Nat, 600, 608, Hd);
    // 14. mol_vecs = mean -> d_out
    mean_kernel<<<Mmol, 320, 0, stream>>>(AH, OUT);
}